// Round 1
// baseline (38827.814 us; speedup 1.0000x reference)
//
#include <hip/hip_runtime.h>
#include <cmath>

// ws float offsets
#define WS_AK 0
#define WS_AV 300
#define WS_DK 600
#define WS_DV (600 + 102400)

// ---------------------------------------------------------------------------
// Precompute Ak/Av: Ak[c][m] = sum_n proj_w[n][c] * k_w[m][n]   (c<3, m<100)
// ---------------------------------------------------------------------------
__global__ void pre_amat_kernel(const float* __restrict__ proj_w,
                                const float* __restrict__ k_w,
                                const float* __restrict__ v_w,
                                float* __restrict__ ws) {
  int idx = blockIdx.x * blockDim.x + threadIdx.x;
  if (idx >= 600) return;
  int sel = idx / 300;
  int rem = idx % 300;
  int c = rem / 100, m = rem % 100;
  const float* w = sel ? v_w : k_w;
  float acc = 0.f;
  for (int n = 0; n < 100; ++n) acc += proj_w[n * 131 + c] * w[m * 100 + n];
  ws[(sel ? WS_AV : WS_AK) + c * 100 + m] = acc;
}

// ---------------------------------------------------------------------------
// Precompute Dk/Dv: batch-independent part of K/V.
// token_const[p][n] = proj_b[n] + sum_f pos[p][f]*proj_w[n][3+f]
// Dk[p][m] = k_b[m] + sum_n token_const[p][n]*k_w[m][n]
// ---------------------------------------------------------------------------
__global__ void pre_dmat_kernel(const float* __restrict__ fm,
                                const float* __restrict__ proj_w,
                                const float* __restrict__ proj_b,
                                const float* __restrict__ k_w,
                                const float* __restrict__ k_b,
                                const float* __restrict__ v_w,
                                const float* __restrict__ v_b,
                                float* __restrict__ ws) {
  __shared__ float pos[8][128];
  __shared__ float tc[8][100];
  int p0 = blockIdx.x * 8;
  int tid = threadIdx.x;
  for (int idx = tid; idx < 1024; idx += 256) {
    int pl = idx >> 7, f = idx & 127;
    int p = p0 + pl;
    float cx = (float)(p & 31) * (1.f / 31.f);
    float cy = (float)(p >> 5) * (1.f / 31.f);
    int fi = f & 63;
    float pr = cx * fm[fi] + cy * fm[64 + fi];
    float ang = 6.2831853071795864769f * pr;
    pos[pl][f] = (f < 64) ? cosf(ang) : sinf(ang);
  }
  __syncthreads();
  for (int idx = tid; idx < 800; idx += 256) {
    int pl = idx / 100, n = idx % 100;
    float acc = proj_b[n];
    const float* pw = proj_w + n * 131 + 3;
    for (int f = 0; f < 128; ++f) acc += pos[pl][f] * pw[f];
    tc[pl][n] = acc;
  }
  __syncthreads();
  for (int idx = tid; idx < 1600; idx += 256) {
    int sel = idx / 800;
    int rem = idx % 800;
    int pl = rem / 100, m = rem % 100;
    const float* w = sel ? v_w : k_w;
    float acc = sel ? v_b[m] : k_b[m];
    for (int n = 0; n < 100; ++n) acc += tc[pl][n] * w[m * 100 + n];
    ws[(sel ? WS_DV : WS_DK) + (p0 + pl) * 100 + m] = acc;
  }
}

// ---------------------------------------------------------------------------
// Main fused kernel: one block per batch item, 512 threads.
// Thread pair (2r, 2r+1) owns latent row r; thread (r,half) holds
// lat[r][half*50 .. half*50+50) in registers.
// LDS: s_w  = weight staging (51.2KB, also final reduce buffer)
//      s_kv = K/V tiles [64][104]x2 or per-head k_h/v_h [256][28]x2 (57.3KB)
//      s_sm = biases / LN params / Ak/Av (13.6KB)
// ---------------------------------------------------------------------------
__launch_bounds__(512, 2)
__global__ void perceiver_kernel(
    const float* __restrict__ x,
    const float* __restrict__ latents,
    const float* __restrict__ latent_pos,
    const float* __restrict__ q_w, const float* __restrict__ q_b,
    const float* __restrict__ o_w, const float* __restrict__ o_b,
    const float* __restrict__ ln1_g, const float* __restrict__ ln1_b,
    const float* __restrict__ attn_in_w, const float* __restrict__ attn_in_b,
    const float* __restrict__ attn_out_w, const float* __restrict__ attn_out_b,
    const float* __restrict__ ln2_g, const float* __restrict__ ln2_b,
    const float* __restrict__ mlp_w1, const float* __restrict__ mlp_b1,
    const float* __restrict__ mlp_w2, const float* __restrict__ mlp_b2,
    const float* __restrict__ ws,
    float* __restrict__ out) {
  __shared__ float s_w[12800];
  __shared__ float s_kv[14336];
  __shared__ float s_sm[3400];

  const int tid = threadIdx.x;
  const int b = blockIdx.x;
  const int r = tid >> 1;
  const int half = tid & 1;
  const int hc = half * 50;   // real channel half base
  const int hb = half * 52;   // padded-104 half base

  // ---- stage small constants (once) ----
  // s_sm layout: 0 q_b[100] | 100 o_b[100] | 200 ln1_g[200] | 400 ln1_b[200]
  // | 600 ln2_g[200] | 800 ln2_b[200] | 1000 attn_in_b[600] | 1600 attn_out_b[200]
  // | 1800 mlp_b1[800] | 2600 mlp_b2[200] | 2800 Ak[300] | 3100 Av[300]
  for (int i = tid; i < 100; i += 512) { s_sm[i] = q_b[i]; s_sm[100 + i] = o_b[i]; }
  for (int i = tid; i < 200; i += 512) {
    s_sm[200 + i] = ln1_g[i]; s_sm[400 + i] = ln1_b[i];
    s_sm[600 + i] = ln2_g[i]; s_sm[800 + i] = ln2_b[i];
    s_sm[1600 + i] = attn_out_b[i]; s_sm[2600 + i] = mlp_b2[i];
  }
  for (int i = tid; i < 600; i += 512) s_sm[1000 + i] = attn_in_b[i];
  for (int i = tid; i < 800; i += 512) s_sm[1800 + i] = mlp_b1[i];
  for (int i = tid; i < 300; i += 512) { s_sm[2800 + i] = ws[WS_AK + i]; s_sm[3100 + i] = ws[WS_AV + i]; }
  // zero tail of s_w: o-proj reads up to s_w[10003] with zero multiplier
  for (int i = 10000 + tid; i < 12800; i += 512) s_w[i] = 0.f;

  float latv[50];
  #pragma unroll
  for (int i = 0; i < 50; ++i)
    latv[i] = latents[r * 100 + hc + i] + latent_pos[r * 100 + hc + i];

  const float* xb = x + (long)b * 3072;

  for (int it = 0; it < 8; ++it) {
    //=================== cross attention ===================
    // --- q = lat @ q_w.T + q_b (padded layout: half0 -> m 0..51, half1 -> m 52..99 + 4 zeros)
    __syncthreads();
    for (int i = tid; i < 10000; i += 512) s_w[i] = q_w[i];
    __syncthreads();

    float qv[52];
    #pragma unroll
    for (int n = 0; n < 52; ++n) {
      const float* wr = &s_w[n * 100 + hc];
      float p0 = 0.f, p1 = 0.f;
      #pragma unroll
      for (int i = 0; i < 50; i += 2) { p0 += latv[i] * wr[i]; p1 += latv[i + 1] * wr[i + 1]; }
      float full = p0 + p1;
      full += __shfl_xor(full, 1);
      if (half == 0) qv[n] = full + s_sm[n];
    }
    #pragma unroll
    for (int n = 52; n < 100; ++n) {
      const float* wr = &s_w[n * 100 + hc];
      float p0 = 0.f, p1 = 0.f;
      #pragma unroll
      for (int i = 0; i < 50; i += 2) { p0 += latv[i] * wr[i]; p1 += latv[i + 1] * wr[i + 1]; }
      float full = p0 + p1;
      full += __shfl_xor(full, 1);
      if (half == 1) qv[n - 52] = full + s_sm[n];
    }
    if (half == 1) { qv[48] = 0.f; qv[49] = 0.f; qv[50] = 0.f; qv[51] = 0.f; }

    // --- flash attention over 16 K/V tiles of 64 positions
    float acc[52];
    #pragma unroll
    for (int i = 0; i < 52; ++i) acc[i] = 0.f;
    float m = -1e30f, l = 0.f;

    for (int t0 = 0; t0 < 1024; t0 += 64) {
      __syncthreads();
      // build k_tile [64][104] at s_kv[0], v_tile at s_kv[6656]
      for (int idx = tid; idx < 13312; idx += 512) {
        int sel = idx >= 6656;
        int rem = sel ? idx - 6656 : idx;
        int jj = rem / 104, mm = rem % 104;
        float val = 0.f;
        if (mm < 100) {
          int p = t0 + jj;
          const float* A = &s_sm[sel ? 3100 : 2800];
          float xr = xb[p], xg = xb[1024 + p], xb2 = xb[2048 + p];
          val = xr * A[mm] + xg * A[100 + mm] + xb2 * A[200 + mm]
              + ws[(sel ? WS_DV : WS_DK) + p * 100 + mm];
        }
        s_kv[(sel ? 6656 : 0) + jj * 104 + mm] = val;
      }
      __syncthreads();

      for (int jj = 0; jj < 64; ++jj) {
        const float4* kt4 = reinterpret_cast<const float4*>(&s_kv[jj * 104 + hb]);
        float p0 = 0.f, p1 = 0.f, p2 = 0.f, p3 = 0.f;
        #pragma unroll
        for (int i2 = 0; i2 < 13; ++i2) {
          float4 kk = kt4[i2];
          p0 += qv[i2 * 4 + 0] * kk.x; p1 += qv[i2 * 4 + 1] * kk.y;
          p2 += qv[i2 * 4 + 2] * kk.z; p3 += qv[i2 * 4 + 3] * kk.w;
        }
        float s = (p0 + p1) + (p2 + p3);
        s += __shfl_xor(s, 1);
        s *= 0.1f;  // 1/sqrt(100)
        float mn = fmaxf(m, s);
        if (mn > m) {
          float f = __expf(m - mn);
          l *= f;
          #pragma unroll
          for (int i = 0; i < 52; ++i) acc[i] *= f;
          m = mn;
        }
        float pe = __expf(s - m);
        l += pe;
        const float4* vt4 = reinterpret_cast<const float4*>(&s_kv[6656 + jj * 104 + hb]);
        #pragma unroll
        for (int i2 = 0; i2 < 13; ++i2) {
          float4 vv = vt4[i2];
          acc[i2 * 4 + 0] += pe * vv.x; acc[i2 * 4 + 1] += pe * vv.y;
          acc[i2 * 4 + 2] += pe * vv.z; acc[i2 * 4 + 3] += pe * vv.w;
        }
      }
    }
    {
      float il = 1.0f / l;
      #pragma unroll
      for (int i = 0; i < 52; ++i) acc[i] *= il;
    }

    // --- lat = (attn@v) @ o_w.T + o_b  (acc pads are zero; tail of s_w zeroed)
    __syncthreads();
    for (int i = tid; i < 10000; i += 512) s_w[i] = o_w[i];
    __syncthreads();

    float nlat[50];
    #pragma unroll
    for (int c = 0; c < 50; ++c) {
      const float* wr = &s_w[c * 100 + hb];
      float partial = 0.f;
      #pragma unroll
      for (int i = 0; i < 52; ++i) partial += acc[i] * wr[i];
      partial += __shfl_xor(partial, 1);
      if (half == 0) nlat[c] = partial + s_sm[100 + c];
    }
    #pragma unroll
    for (int c = 50; c < 100; ++c) {
      const float* wr = &s_w[c * 100 + hb];
      float partial = 0.f;
      #pragma unroll
      for (int i = 0; i < 52; ++i) partial += acc[i] * wr[i];
      partial += __shfl_xor(partial, 1);
      if (half == 1) nlat[c - 50] = partial + s_sm[100 + c];
    }
    #pragma unroll
    for (int i = 0; i < 50; ++i) latv[i] = nlat[i];

    //=================== latent transformer ===================
    for (int d = 0; d < 2; ++d) {
      // ---- LN1 -> hv
      float hv[50];
      {
        float s = 0.f, sq = 0.f;
        #pragma unroll
        for (int i = 0; i < 50; ++i) { s += latv[i]; sq += latv[i] * latv[i]; }
        s += __shfl_xor(s, 1); sq += __shfl_xor(sq, 1);
        float mu = s * 0.01f;
        float var = sq * 0.01f - mu * mu;
        float rs = rsqrtf(var + 1e-5f);
        #pragma unroll
        for (int i = 0; i < 50; ++i)
          hv[i] = (latv[i] - mu) * rs * s_sm[200 + d * 100 + hc + i] + s_sm[400 + d * 100 + hc + i];
      }

      // ---- MHA: 4 heads, hd=25 (padded to 28)
      for (int h = 0; h < 4; ++h) {
        __syncthreads();
        // stage wq[25][100] @0, wk @2500, wv @5000, wout[100][25] @7500
        for (int idx = tid; idx < 7500; idx += 512) {
          int rr = idx / 100, c = idx % 100;
          int which = rr / 25, dh = rr % 25;
          int grow = which * 100 + h * 25 + dh;
          s_w[idx] = attn_in_w[d * 30000 + grow * 100 + c];
        }
        for (int idx = tid; idx < 2500; idx += 512) {
          int c = idx / 25, dh = idx % 25;
          s_w[7500 + idx] = attn_out_w[d * 10000 + c * 100 + h * 25 + dh];
        }
        __syncthreads();

        // build k_h [256][28] @ s_kv[0], v_h @ s_kv[7168]
        for (int dh = 0; dh < 25; ++dh) {
          const float* wk = &s_w[2500 + dh * 100 + hc];
          const float* wv = &s_w[5000 + dh * 100 + hc];
          float pk = 0.f, pv = 0.f;
          #pragma unroll
          for (int i = 0; i < 50; ++i) { pk += hv[i] * wk[i]; pv += hv[i] * wv[i]; }
          pk += __shfl_xor(pk, 1); pv += __shfl_xor(pv, 1);
          pk += s_sm[1000 + d * 300 + 100 + h * 25 + dh];
          pv += s_sm[1000 + d * 300 + 200 + h * 25 + dh];
          if (half == 0) s_kv[r * 28 + dh] = pk;
          else           s_kv[7168 + r * 28 + dh] = pv;
        }
        if (half == 0) { s_kv[r * 28 + 25] = 0.f; s_kv[r * 28 + 26] = 0.f; s_kv[r * 28 + 27] = 0.f; }
        else { s_kv[7168 + r * 28 + 25] = 0.f; s_kv[7168 + r * 28 + 26] = 0.f; s_kv[7168 + r * 28 + 27] = 0.f; }

        // q_h (both threads of pair hold full 25, padded to 28)
        float qh[28];
        #pragma unroll
        for (int dh = 0; dh < 25; ++dh) {
          const float* wq = &s_w[dh * 100 + hc];
          float p = 0.f;
          #pragma unroll
          for (int i = 0; i < 50; ++i) p += hv[i] * wq[i];
          p += __shfl_xor(p, 1);
          qh[dh] = p + s_sm[1000 + d * 300 + h * 25 + dh];
        }
        qh[25] = 0.f; qh[26] = 0.f; qh[27] = 0.f;
        __syncthreads();

        // flash over my half of j (half0: 0..127, half1: 128..255)
        float am = -1e30f, al = 0.f;
        float aacc[28];
        #pragma unroll
        for (int i = 0; i < 28; ++i) aacc[i] = 0.f;
        const int j0 = half * 128;
        for (int jj = 0; jj < 128; ++jj) {
          const float4* kr = reinterpret_cast<const float4*>(&s_kv[(j0 + jj) * 28]);
          float p0 = 0.f, p1 = 0.f, p2 = 0.f, p3 = 0.f;
          #pragma unroll
          for (int i2 = 0; i2 < 7; ++i2) {
            float4 kk = kr[i2];
            p0 += qh[i2 * 4 + 0] * kk.x; p1 += qh[i2 * 4 + 1] * kk.y;
            p2 += qh[i2 * 4 + 2] * kk.z; p3 += qh[i2 * 4 + 3] * kk.w;
          }
          float sc = ((p0 + p1) + (p2 + p3)) * 0.2f;  // 1/sqrt(25)
          float mn = fmaxf(am, sc);
          if (mn > am) {
            float f = __expf(am - mn);
            al *= f;
            #pragma unroll
            for (int i = 0; i < 28; ++i) aacc[i] *= f;
            am = mn;
          }
          float pe = __expf(sc - am);
          al += pe;
          const float4* vr = reinterpret_cast<const float4*>(&s_kv[7168 + (j0 + jj) * 28]);
          #pragma unroll
          for (int i2 = 0; i2 < 7; ++i2) {
            float4 vv = vr[i2];
            aacc[i2 * 4 + 0] += pe * vv.x; aacc[i2 * 4 + 1] += pe * vv.y;
            aacc[i2 * 4 + 2] += pe * vv.z; aacc[i2 * 4 + 3] += pe * vv.w;
          }
        }
        // merge the two halves of the pair
        float mo = __shfl_xor(am, 1);
        float mn2 = fmaxf(am, mo);
        float f = __expf(am - mn2);
        float lf = al * f;
        float ltot = lf + __shfl_xor(lf, 1);
        float inv = 1.0f / ltot;
        float oh[25];
        #pragma unroll
        for (int i = 0; i < 25; ++i) {
          float a = aacc[i] * f;
          a += __shfl_xor(a, 1);
          oh[i] = a * inv;
        }
        // residual: lat += o_h @ out_w[:, h*25:(h+1)*25].T
        #pragma unroll
        for (int cl = 0; cl < 50; ++cl) {
          const float* wo = &s_w[7500 + (hc + cl) * 25];
          float p = 0.f;
          #pragma unroll
          for (int dh = 0; dh < 25; ++dh) p += oh[dh] * wo[dh];
          latv[cl] += p;
        }
      }
      // MHA output bias (added once)
      #pragma unroll
      for (int i = 0; i < 50; ++i) latv[i] += s_sm[1600 + d * 100 + hc + i];

      // ---- LN2 -> hv
      {
        float s = 0.f, sq = 0.f;
        #pragma unroll
        for (int i = 0; i < 50; ++i) { s += latv[i]; sq += latv[i] * latv[i]; }
        s += __shfl_xor(s, 1); sq += __shfl_xor(sq, 1);
        float mu = s * 0.01f;
        float var = sq * 0.01f - mu * mu;
        float rs = rsqrtf(var + 1e-5f);
        #pragma unroll
        for (int i = 0; i < 50; ++i)
          hv[i] = (latv[i] - mu) * rs * s_sm[600 + d * 100 + hc + i] + s_sm[800 + d * 100 + hc + i];
      }

      // ---- MLP: 400 hidden, exact GELU; j-tiles of 50
      float aout[50];
      #pragma unroll
      for (int i = 0; i < 50; ++i) aout[i] = 0.f;
      for (int jt = 0; jt < 400; jt += 50) {
        __syncthreads();
        for (int idx = tid; idx < 5000; idx += 512) {
          int jl = idx / 100, c = idx % 100;
          s_w[idx] = mlp_w1[d * 40000 + (jt + jl) * 100 + c];
        }
        for (int idx = tid; idx < 5000; idx += 512) {
          int jl = idx % 50, c = idx / 50;
          s_w[5000 + jl * 100 + c] = mlp_w2[d * 40000 + c * 400 + jt + jl];
        }
        __syncthreads();
        for (int jl = 0; jl < 50; ++jl) {
          const float* w1r = &s_w[jl * 100 + hc];
          float p0 = 0.f, p1 = 0.f;
          #pragma unroll
          for (int i = 0; i < 50; i += 2) { p0 += hv[i] * w1r[i]; p1 += hv[i + 1] * w1r[i + 1]; }
          float hid = p0 + p1;
          hid += __shfl_xor(hid, 1);
          hid += s_sm[1800 + d * 400 + jt + jl];
          float g = hid * 0.5f * (1.0f + erff(hid * 0.70710678118654752f));
          const float* w2r = &s_w[5000 + jl * 100 + hc];
          #pragma unroll
          for (int cl = 0; cl < 50; ++cl) aout[cl] += g * w2r[cl];
        }
      }
      #pragma unroll
      for (int i = 0; i < 50; ++i) latv[i] += aout[i] + s_sm[2600 + d * 100 + hc + i];
    }
  }

  //=================== mean over 256 latents ===================
  for (int w = 128; w >= 1; w >>= 1) {
    __syncthreads();
    if (r >= w && r < 2 * w) {
      #pragma unroll
      for (int i = 0; i < 50; ++i) s_w[(r - w) * 100 + hc + i] = latv[i];
    }
    __syncthreads();
    if (r < w) {
      #pragma unroll
      for (int i = 0; i < 50; ++i) latv[i] += s_w[r * 100 + hc + i];
    }
  }
  if (r == 0) {
    #pragma unroll
    for (int i = 0; i < 50; ++i) out[b * 100 + hc + i] = latv[i] * (1.0f / 256.0f);
  }
}

// ---------------------------------------------------------------------------
extern "C" void kernel_launch(void* const* d_in, const int* in_sizes, int n_in,
                              void* d_out, int out_size, void* d_ws, size_t ws_size,
                              hipStream_t stream) {
  (void)in_sizes; (void)n_in; (void)out_size; (void)ws_size;
  const float* x          = (const float*)d_in[0];
  const float* latents    = (const float*)d_in[1];
  const float* latent_pos = (const float*)d_in[2];
  const float* fm         = (const float*)d_in[3];
  const float* proj_w     = (const float*)d_in[4];
  const float* proj_b     = (const float*)d_in[5];
  const float* q_w        = (const float*)d_in[6];
  const float* q_b        = (const float*)d_in[7];
  const float* k_w        = (const float*)d_in[8];
  const float* k_b        = (const float*)d_in[9];
  const float* v_w        = (const float*)d_in[10];
  const float* v_b        = (const float*)d_in[11];
  const float* o_w        = (const float*)d_in[12];
  const float* o_b        = (const float*)d_in[13];
  const float* ln1_g      = (const float*)d_in[14];
  const float* ln1_b      = (const float*)d_in[15];
  const float* attn_in_w  = (const float*)d_in[16];
  const float* attn_in_b  = (const float*)d_in[17];
  const float* attn_out_w = (const float*)d_in[18];
  const float* attn_out_b = (const float*)d_in[19];
  const float* ln2_g      = (const float*)d_in[20];
  const float* ln2_b      = (const float*)d_in[21];
  const float* mlp_w1     = (const float*)d_in[22];
  const float* mlp_b1     = (const float*)d_in[23];
  const float* mlp_w2     = (const float*)d_in[24];
  const float* mlp_b2     = (const float*)d_in[25];
  float* ws   = (float*)d_ws;
  float* outp = (float*)d_out;

  pre_amat_kernel<<<3, 256, 0, stream>>>(proj_w, k_w, v_w, ws);
  pre_dmat_kernel<<<128, 256, 0, stream>>>(fm, proj_w, proj_b, k_w, k_b, v_w, v_b, ws);
  perceiver_kernel<<<512, 512, 0, stream>>>(
      x, latents, latent_pos, q_w, q_b, o_w, o_b,
      ln1_g, ln1_b, attn_in_w, attn_in_b, attn_out_w, attn_out_b,
      ln2_g, ln2_b, mlp_w1, mlp_b1, mlp_w2, mlp_b2, ws, outp);
}

// Round 2
// 21412.180 us; speedup vs baseline: 1.8134x; 1.8134x over previous
//
#include <hip/hip_runtime.h>
#include <cmath>

// ws float offsets
#define WS_AK 0
#define WS_AV 300
#define WS_DK 600
#define WS_DV 103000
#define WS_BF 205400   // float offset where bf16 weight-fragment region starts

// bf16 fragment-region offsets (in ushorts, relative to ws+WS_BF)
#define WSB_QW 0
#define WSB_OW 14336
#define WSB_W1 28672     // + d*51200   (kt=4, nt=25)
#define WSB_W2 131072    // + d*50176   (kt=14, nt=7)
#define WSB_TOTAL 231424

typedef __attribute__((ext_vector_type(8))) short short8;
typedef __attribute__((ext_vector_type(4))) float f32x4;

#define MFMA(a, b, c) __builtin_amdgcn_mfma_f32_16x16x32_bf16((a), (b), (c), 0, 0, 0)

static __device__ __forceinline__ unsigned short f2bf(float f) {
  unsigned int u = __float_as_uint(f);
  u += 0x7FFF + ((u >> 16) & 1);   // RNE
  return (unsigned short)(u >> 16);
}

// ---------------------------------------------------------------------------
// Precompute Ak/Av: Ak[c][m] = sum_n proj_w[n][c] * k_w[m][n]
// ---------------------------------------------------------------------------
__global__ void pre_amat_kernel(const float* __restrict__ proj_w,
                                const float* __restrict__ k_w,
                                const float* __restrict__ v_w,
                                float* __restrict__ ws) {
  int idx = blockIdx.x * blockDim.x + threadIdx.x;
  if (idx >= 600) return;
  int sel = idx / 300;
  int rem = idx % 300;
  int c = rem / 100, m = rem % 100;
  const float* w = sel ? v_w : k_w;
  float acc = 0.f;
  for (int n = 0; n < 100; ++n) acc += proj_w[n * 131 + c] * w[m * 100 + n];
  ws[(sel ? WS_AV : WS_AK) + c * 100 + m] = acc;
}

// ---------------------------------------------------------------------------
// Precompute Dk/Dv (batch-independent part of K/V)
// ---------------------------------------------------------------------------
__global__ void pre_dmat_kernel(const float* __restrict__ fm,
                                const float* __restrict__ proj_w,
                                const float* __restrict__ proj_b,
                                const float* __restrict__ k_w,
                                const float* __restrict__ k_b,
                                const float* __restrict__ v_w,
                                const float* __restrict__ v_b,
                                float* __restrict__ ws) {
  __shared__ float pos[8][128];
  __shared__ float tc[8][100];
  int p0 = blockIdx.x * 8;
  int tid = threadIdx.x;
  for (int idx = tid; idx < 1024; idx += 256) {
    int pl = idx >> 7, f = idx & 127;
    int p = p0 + pl;
    float cx = (float)(p & 31) * (1.f / 31.f);
    float cy = (float)(p >> 5) * (1.f / 31.f);
    int fi = f & 63;
    float pr = cx * fm[fi] + cy * fm[64 + fi];
    float ang = 6.2831853071795864769f * pr;
    pos[pl][f] = (f < 64) ? cosf(ang) : sinf(ang);
  }
  __syncthreads();
  for (int idx = tid; idx < 800; idx += 256) {
    int pl = idx / 100, n = idx % 100;
    float acc = proj_b[n];
    const float* pw = proj_w + n * 131 + 3;
    for (int f = 0; f < 128; ++f) acc += pos[pl][f] * pw[f];
    tc[pl][n] = acc;
  }
  __syncthreads();
  for (int idx = tid; idx < 1600; idx += 256) {
    int sel = idx / 800;
    int rem = idx % 800;
    int pl = rem / 100, m = rem % 100;
    const float* w = sel ? v_w : k_w;
    float acc = sel ? v_b[m] : k_b[m];
    for (int n = 0; n < 100; ++n) acc += tc[pl][n] * w[m * 100 + n];
    ws[(sel ? WS_DV : WS_DK) + (p0 + pl) * 100 + m] = acc;
  }
}

// ---------------------------------------------------------------------------
// Pre-convert GEMM weights to bf16 B-fragment-linear layout:
// offset = ((kt*NT + nt)*64 + lane)*8 + j ; element = B[k][n],
// k = kt*32 + (lane>>4)*8 + j ; n = nt*16 + (lane&15) ; B[k][n] = W[n][k].
// ---------------------------------------------------------------------------
__global__ void pre_wfrag_kernel(const float* __restrict__ q_w,
                                 const float* __restrict__ o_w,
                                 const float* __restrict__ mlp_w1,
                                 const float* __restrict__ mlp_w2,
                                 unsigned short* __restrict__ wsb) {
  int idx = blockIdx.x * 256 + threadIdx.x;
  if (idx >= WSB_TOTAL) return;
  float val = 0.f;
  if (idx < 14336) {                       // QW: kt4 x nt7
    int rem = idx;
    int kt = rem / 3584; rem %= 3584;
    int nt = rem / 512;  rem %= 512;
    int lane = rem >> 3, j = rem & 7;
    int k = kt * 32 + (lane >> 4) * 8 + j;
    int n = nt * 16 + (lane & 15);
    if (k < 100 && n < 100) val = q_w[n * 100 + k];
  } else if (idx < 28672) {                // OW: kt4 x nt7
    int rem = idx - 14336;
    int kt = rem / 3584; rem %= 3584;
    int nt = rem / 512;  rem %= 512;
    int lane = rem >> 3, j = rem & 7;
    int k = kt * 32 + (lane >> 4) * 8 + j;
    int n = nt * 16 + (lane & 15);
    if (k < 100 && n < 100) val = o_w[n * 100 + k];
  } else if (idx < 131072) {               // W1[d]: kt4 x nt25
    int off = idx - 28672;
    int d = off / 51200;
    int rem = off % 51200;
    int kt = rem / 12800; rem %= 12800;
    int nt = rem / 512;   rem %= 512;
    int lane = rem >> 3, j = rem & 7;
    int k = kt * 32 + (lane >> 4) * 8 + j;
    int n = nt * 16 + (lane & 15);       // n < 400 always
    if (k < 100) val = mlp_w1[d * 40000 + n * 100 + k];
  } else {                                  // W2[d]: kt14 x nt7
    int off = idx - 131072;
    int d = off / 50176;
    int rem = off % 50176;
    int kt = rem / 3584; rem %= 3584;
    int nt = rem / 512;  rem %= 512;
    int lane = rem >> 3, j = rem & 7;
    int k = kt * 32 + (lane >> 4) * 8 + j;
    int n = nt * 16 + (lane & 15);
    if (k < 400 && n < 100) val = mlp_w2[d * 40000 + n * 400 + k];
  }
  wsb[idx] = f2bf(val);
}

// ---------------------------------------------------------------------------
// Main fused kernel: one block per batch item, 512 threads (8 waves).
// Wave w owns latent rows [32w, 32w+32)  (MFMA m-tiles MT = 2w, 2w+1).
// Scalar residual state: thread pair (2r,2r+1) holds lat[r][half*50..+50) f32.
// LDS pool (152.8 KB), phase-aliased:
//   s_sm   [0,3400) floats: biases/LN/Ak/Av
//   reg0   34816 floats:
//     s_M  = bf16 [256][136] A-matrix #1 (lat/q/o_in/h)
//     s_Hb = bf16 region #2: attn { sK[16][64][8] | sV[8][112][8] | sP[256][72] }
//            or MLP hid [256][136]
//     s_x  = f32 [256][104] exchange   (aliases s_M+s_Hb, phase-disjoint)
//     s_w/s_kv = scalar MHA staging    (aliases,           phase-disjoint)
// ---------------------------------------------------------------------------
__launch_bounds__(512, 1)
__global__ void perceiver_kernel(
    const float* __restrict__ x,
    const float* __restrict__ latents,
    const float* __restrict__ latent_pos,
    const float* __restrict__ q_b, const float* __restrict__ o_b,
    const float* __restrict__ ln1_g, const float* __restrict__ ln1_b,
    const float* __restrict__ attn_in_w, const float* __restrict__ attn_in_b,
    const float* __restrict__ attn_out_w, const float* __restrict__ attn_out_b,
    const float* __restrict__ ln2_g, const float* __restrict__ ln2_b,
    const float* __restrict__ mlp_b1, const float* __restrict__ mlp_b2,
    const float* __restrict__ ws,
    float* __restrict__ out) {
  __shared__ __align__(16) float s_pool[38216];
  float* s_sm = s_pool;
  float* reg0 = s_pool + 3400;
  unsigned short* s_M  = (unsigned short*)reg0;            // [256][136] bf16
  unsigned short* s_Hb = (unsigned short*)(reg0 + 17408);  // 34816 ushorts
  unsigned short* sK = s_Hb;                                // [16][64][8]
  unsigned short* sV = s_Hb + 8192;                         // [8][112][8]
  unsigned short* sP = s_Hb + 15360;                        // [256][72]
  float* s_x  = reg0;                                       // [256][104] f32
  float* s_w  = reg0;                                       // scalar MHA: 10000
  float* s_kv = reg0 + 10000;                               // scalar MHA: 14336

  const int tid  = threadIdx.x;
  const int b    = blockIdx.x;
  const int r    = tid >> 1;
  const int half = tid & 1;
  const int hc   = half * 50;
  const int lane = tid & 63;
  const int wv   = tid >> 6;
  const int li   = lane & 15;
  const int lg   = lane >> 4;
  const unsigned short* wsb = (const unsigned short*)(ws + WS_BF);

  // ---- stage small constants ----
  for (int i = tid; i < 100; i += 512) { s_sm[i] = q_b[i]; s_sm[100 + i] = o_b[i]; }
  for (int i = tid; i < 200; i += 512) {
    s_sm[200 + i] = ln1_g[i]; s_sm[400 + i] = ln1_b[i];
    s_sm[600 + i] = ln2_g[i]; s_sm[800 + i] = ln2_b[i];
    s_sm[1600 + i] = attn_out_b[i]; s_sm[2600 + i] = mlp_b2[i];
  }
  for (int i = tid; i < 600; i += 512) s_sm[1000 + i] = attn_in_b[i];
  for (int i = tid; i < 800; i += 512) s_sm[1800 + i] = mlp_b1[i];
  for (int i = tid; i < 300; i += 512) { s_sm[2800 + i] = ws[WS_AK + i]; s_sm[3100 + i] = ws[WS_AV + i]; }

  float latv[50];
  #pragma unroll
  for (int i = 0; i < 50; ++i)
    latv[i] = latents[r * 100 + hc + i] + latent_pos[r * 100 + hc + i];

  const float* xb = x + (long)b * 3072;

  for (int it = 0; it < 8; ++it) {
    //=================== cross attention (MFMA) ===================
    __syncthreads();   // region reuse (s_x / MHA buffers from previous phase)
    // lat -> s_M bf16 rows + zero k-pads (cols 100..127)
    #pragma unroll
    for (int i = 0; i < 50; ++i) s_M[r * 136 + hc + i] = f2bf(latv[i]);
    #pragma unroll
    for (int i = 0; i < 14; ++i) s_M[r * 136 + 100 + half * 14 + i] = 0;
    __syncthreads();

    // ---- q-proj: q = (lat @ q_w^T + q_b) * 0.1 -> s_M (overwrite, bf16)
    {
      f32x4 qacc[2][7];
      #pragma unroll
      for (int a0 = 0; a0 < 2; ++a0)
        #pragma unroll
        for (int a1 = 0; a1 < 7; ++a1) qacc[a0][a1] = (f32x4){0.f, 0.f, 0.f, 0.f};
      short8 aq[2][4];
      #pragma unroll
      for (int mt2 = 0; mt2 < 2; ++mt2)
        #pragma unroll
        for (int kt = 0; kt < 4; ++kt)
          aq[mt2][kt] = *(const short8*)(s_M + ((2 * wv + mt2) * 16 + li) * 136 + kt * 32 + lg * 8);
      #pragma unroll
      for (int nt = 0; nt < 7; ++nt)
        #pragma unroll
        for (int kt = 0; kt < 4; ++kt) {
          short8 bw = *(const short8*)(wsb + WSB_QW + ((kt * 7 + nt) * 64 + lane) * 8);
          #pragma unroll
          for (int mt2 = 0; mt2 < 2; ++mt2) qacc[mt2][nt] = MFMA(aq[mt2][kt], bw, qacc[mt2][nt]);
        }
      #pragma unroll
      for (int mt2 = 0; mt2 < 2; ++mt2)
        #pragma unroll
        for (int nt = 0; nt < 7; ++nt) {
          int col = nt * 16 + li;
          if (col < 100) {
            #pragma unroll
            for (int rg = 0; rg < 4; ++rg) {
              int row = (2 * wv + mt2) * 16 + lg * 4 + rg;
              s_M[row * 136 + col] = f2bf((qacc[mt2][nt][rg] + s_sm[col]) * 0.1f);
            }
          }
        }
    }

    // ---- attention: S = q@K^T (no-max softmax), O = exp(S)@[V|1]
    f32x4 O[2][7];
    #pragma unroll
    for (int a0 = 0; a0 < 2; ++a0)
      #pragma unroll
      for (int a1 = 0; a1 < 7; ++a1) O[a0][a1] = (f32x4){0.f, 0.f, 0.f, 0.f};
    short8 aq2[2][4];
    #pragma unroll
    for (int mt2 = 0; mt2 < 2; ++mt2)
      #pragma unroll
      for (int kt = 0; kt < 4; ++kt)
        aq2[mt2][kt] = *(const short8*)(s_M + ((2 * wv + mt2) * 16 + li) * 136 + kt * 32 + lg * 8);

    for (int t0 = 0; t0 < 1024; t0 += 64) {
      __syncthreads();   // all waves done reading previous sK/sV
      // build K-tile [chan 128 pad][key 64] frag-linear
      for (int idx = tid; idx < 8192; idx += 512) {
        int j = idx & 7, key = (idx >> 3) & 63, cg = idx >> 9;
        int c = cg * 8 + j;
        float val = 0.f;
        if (c < 100) {
          int p = t0 + key;
          float xr = xb[p], xg = xb[1024 + p], xbv = xb[2048 + p];
          val = xr * s_sm[2800 + c] + xg * s_sm[2900 + c] + xbv * s_sm[3000 + c]
              + ws[WS_DK + p * 100 + c];
        }
        sK[idx] = f2bf(val);
      }
      // build V-tile [key 64][chan 112: 100 real, col100=1, rest 0] frag-linear
      for (int idx = tid; idx < 7168; idx += 512) {
        int j = idx & 7, ch = (idx >> 3) % 112, kg = idx / 896;
        int key = kg * 8 + j;
        int p = t0 + key;
        float val;
        if (ch < 100) {
          float xr = xb[p], xg = xb[1024 + p], xbv = xb[2048 + p];
          val = xr * s_sm[3100 + ch] + xg * s_sm[3200 + ch] + xbv * s_sm[3300 + ch]
              + ws[WS_DV + p * 100 + ch];
        } else val = (ch == 100) ? 1.0f : 0.f;
        sV[idx] = f2bf(val);
      }
      __syncthreads();

      // S-GEMM + exp -> sP (bf16)
      #pragma unroll
      for (int ntk = 0; ntk < 4; ++ntk) {
        short8 bk[4];
        #pragma unroll
        for (int kt = 0; kt < 4; ++kt)
          bk[kt] = *(const short8*)(sK + ((kt * 4 + lg) * 64 + ntk * 16 + li) * 8);
        #pragma unroll
        for (int mt2 = 0; mt2 < 2; ++mt2) {
          f32x4 sres = (f32x4){0.f, 0.f, 0.f, 0.f};
          #pragma unroll
          for (int kt = 0; kt < 4; ++kt) sres = MFMA(aq2[mt2][kt], bk[kt], sres);
          #pragma unroll
          for (int rg = 0; rg < 4; ++rg) {
            int row = (2 * wv + mt2) * 16 + lg * 4 + rg;
            sP[row * 72 + ntk * 16 + li] = f2bf(__expf(sres[rg]));
          }
        }
      }
      // PV accumulate
      short8 ap[2][2];
      #pragma unroll
      for (int mt2 = 0; mt2 < 2; ++mt2)
        #pragma unroll
        for (int kt2 = 0; kt2 < 2; ++kt2)
          ap[mt2][kt2] = *(const short8*)(sP + ((2 * wv + mt2) * 16 + li) * 72 + kt2 * 32 + lg * 8);
      #pragma unroll
      for (int nt = 0; nt < 7; ++nt) {
        short8 bv0 = *(const short8*)(sV + ((0 + lg) * 112 + nt * 16 + li) * 8);
        short8 bv1 = *(const short8*)(sV + ((4 + lg) * 112 + nt * 16 + li) * 8);
        #pragma unroll
        for (int mt2 = 0; mt2 < 2; ++mt2) {
          O[mt2][nt] = MFMA(ap[mt2][0], bv0, O[mt2][nt]);
          O[mt2][nt] = MFMA(ap[mt2][1], bv1, O[mt2][nt]);
        }
      }
    }

    // ---- normalize (l at col 100 -> nt=6, li==4) and write o_in -> s_M
    {
      float linv[2][4];
      #pragma unroll
      for (int mt2 = 0; mt2 < 2; ++mt2)
        #pragma unroll
        for (int rg = 0; rg < 4; ++rg) {
          float lv = __shfl(O[mt2][6][rg], (lane & 48) + 4);
          linv[mt2][rg] = 1.0f / lv;
        }
      #pragma unroll
      for (int mt2 = 0; mt2 < 2; ++mt2)
        #pragma unroll
        for (int nt = 0; nt < 7; ++nt) {
          int col = nt * 16 + li;
          if (col < 100) {
            #pragma unroll
            for (int rg = 0; rg < 4; ++rg) {
              int row = (2 * wv + mt2) * 16 + lg * 4 + rg;
              s_M[row * 136 + col] = f2bf(O[mt2][nt][rg] * linv[mt2][rg]);
            }
          }
        }
    }

    // ---- o-proj: lat' = o_in @ o_w^T + o_b  -> s_x -> latv (replace)
    {
      f32x4 lacc[2][7];
      #pragma unroll
      for (int a0 = 0; a0 < 2; ++a0)
        #pragma unroll
        for (int a1 = 0; a1 < 7; ++a1) lacc[a0][a1] = (f32x4){0.f, 0.f, 0.f, 0.f};
      short8 ao[2][4];
      #pragma unroll
      for (int mt2 = 0; mt2 < 2; ++mt2)
        #pragma unroll
        for (int kt = 0; kt < 4; ++kt)
          ao[mt2][kt] = *(const short8*)(s_M + ((2 * wv + mt2) * 16 + li) * 136 + kt * 32 + lg * 8);
      #pragma unroll
      for (int nt = 0; nt < 7; ++nt)
        #pragma unroll
        for (int kt = 0; kt < 4; ++kt) {
          short8 bw = *(const short8*)(wsb + WSB_OW + ((kt * 7 + nt) * 64 + lane) * 8);
          #pragma unroll
          for (int mt2 = 0; mt2 < 2; ++mt2) lacc[mt2][nt] = MFMA(ao[mt2][kt], bw, lacc[mt2][nt]);
        }
      __syncthreads();   // everyone done reading s_M before s_x overwrite
      #pragma unroll
      for (int mt2 = 0; mt2 < 2; ++mt2)
        #pragma unroll
        for (int nt = 0; nt < 7; ++nt) {
          int col = nt * 16 + li;
          if (col < 100) {
            #pragma unroll
            for (int rg = 0; rg < 4; ++rg) {
              int row = (2 * wv + mt2) * 16 + lg * 4 + rg;
              s_x[row * 104 + col] = lacc[mt2][nt][rg] + s_sm[100 + col];
            }
          }
        }
      __syncthreads();
      #pragma unroll
      for (int i = 0; i < 50; ++i) latv[i] = s_x[r * 104 + hc + i];
      __syncthreads();
    }

    //=================== latent transformer ===================
    for (int d = 0; d < 2; ++d) {
      // ---- LN1 -> hv
      float hv[50];
      {
        float s = 0.f, sq = 0.f;
        #pragma unroll
        for (int i = 0; i < 50; ++i) { s += latv[i]; sq += latv[i] * latv[i]; }
        s += __shfl_xor(s, 1); sq += __shfl_xor(sq, 1);
        float mu = s * 0.01f;
        float var = sq * 0.01f - mu * mu;
        float rs = rsqrtf(var + 1e-5f);
        #pragma unroll
        for (int i = 0; i < 50; ++i)
          hv[i] = (latv[i] - mu) * rs * s_sm[200 + d * 100 + hc + i] + s_sm[400 + d * 100 + hc + i];
      }

      // ---- MHA (scalar, unchanged): 4 heads, hd=25 (padded to 28)
      for (int h = 0; h < 4; ++h) {
        __syncthreads();
        for (int idx = tid; idx < 7500; idx += 512) {
          int rr = idx / 100, c = idx % 100;
          int which = rr / 25, dh = rr % 25;
          int grow = which * 100 + h * 25 + dh;
          s_w[idx] = attn_in_w[d * 30000 + grow * 100 + c];
        }
        for (int idx = tid; idx < 2500; idx += 512) {
          int c = idx / 25, dh = idx % 25;
          s_w[7500 + idx] = attn_out_w[d * 10000 + c * 100 + h * 25 + dh];
        }
        __syncthreads();

        for (int dh = 0; dh < 25; ++dh) {
          const float* wk = &s_w[2500 + dh * 100 + hc];
          const float* wvv = &s_w[5000 + dh * 100 + hc];
          float pk = 0.f, pv = 0.f;
          #pragma unroll
          for (int i = 0; i < 50; ++i) { pk += hv[i] * wk[i]; pv += hv[i] * wvv[i]; }
          pk += __shfl_xor(pk, 1); pv += __shfl_xor(pv, 1);
          pk += s_sm[1000 + d * 300 + 100 + h * 25 + dh];
          pv += s_sm[1000 + d * 300 + 200 + h * 25 + dh];
          if (half == 0) s_kv[r * 28 + dh] = pk;
          else           s_kv[7168 + r * 28 + dh] = pv;
        }
        if (half == 0) { s_kv[r * 28 + 25] = 0.f; s_kv[r * 28 + 26] = 0.f; s_kv[r * 28 + 27] = 0.f; }
        else { s_kv[7168 + r * 28 + 25] = 0.f; s_kv[7168 + r * 28 + 26] = 0.f; s_kv[7168 + r * 28 + 27] = 0.f; }

        float qh[28];
        #pragma unroll
        for (int dh = 0; dh < 25; ++dh) {
          const float* wq = &s_w[dh * 100 + hc];
          float p = 0.f;
          #pragma unroll
          for (int i = 0; i < 50; ++i) p += hv[i] * wq[i];
          p += __shfl_xor(p, 1);
          qh[dh] = p + s_sm[1000 + d * 300 + h * 25 + dh];
        }
        qh[25] = 0.f; qh[26] = 0.f; qh[27] = 0.f;
        __syncthreads();

        float am = -1e30f, al = 0.f;
        float aacc[28];
        #pragma unroll
        for (int i = 0; i < 28; ++i) aacc[i] = 0.f;
        const int j0 = half * 128;
        for (int jj = 0; jj < 128; ++jj) {
          const float4* kr = reinterpret_cast<const float4*>(&s_kv[(j0 + jj) * 28]);
          float p0 = 0.f, p1 = 0.f, p2 = 0.f, p3 = 0.f;
          #pragma unroll
          for (int i2 = 0; i2 < 7; ++i2) {
            float4 kk = kr[i2];
            p0 += qh[i2 * 4 + 0] * kk.x; p1 += qh[i2 * 4 + 1] * kk.y;
            p2 += qh[i2 * 4 + 2] * kk.z; p3 += qh[i2 * 4 + 3] * kk.w;
          }
          float sc = ((p0 + p1) + (p2 + p3)) * 0.2f;
          float mn = fmaxf(am, sc);
          if (mn > am) {
            float f = __expf(am - mn);
            al *= f;
            #pragma unroll
            for (int i = 0; i < 28; ++i) aacc[i] *= f;
            am = mn;
          }
          float pe = __expf(sc - am);
          al += pe;
          const float4* vr = reinterpret_cast<const float4*>(&s_kv[7168 + (j0 + jj) * 28]);
          #pragma unroll
          for (int i2 = 0; i2 < 7; ++i2) {
            float4 vvv = vr[i2];
            aacc[i2 * 4 + 0] += pe * vvv.x; aacc[i2 * 4 + 1] += pe * vvv.y;
            aacc[i2 * 4 + 2] += pe * vvv.z; aacc[i2 * 4 + 3] += pe * vvv.w;
          }
        }
        float mo = __shfl_xor(am, 1);
        float mn2 = fmaxf(am, mo);
        float f = __expf(am - mn2);
        float lf = al * f;
        float ltot = lf + __shfl_xor(lf, 1);
        float inv = 1.0f / ltot;
        float oh[25];
        #pragma unroll
        for (int i = 0; i < 25; ++i) {
          float a = aacc[i] * f;
          a += __shfl_xor(a, 1);
          oh[i] = a * inv;
        }
        #pragma unroll
        for (int cl = 0; cl < 50; ++cl) {
          const float* wo = &s_w[7500 + (hc + cl) * 25];
          float p = 0.f;
          #pragma unroll
          for (int dh = 0; dh < 25; ++dh) p += oh[dh] * wo[dh];
          latv[cl] += p;
        }
      }
      #pragma unroll
      for (int i = 0; i < 50; ++i) latv[i] += s_sm[1600 + d * 100 + hc + i];

      // ---- LN2 -> hv
      {
        float s = 0.f, sq = 0.f;
        #pragma unroll
        for (int i = 0; i < 50; ++i) { s += latv[i]; sq += latv[i] * latv[i]; }
        s += __shfl_xor(s, 1); sq += __shfl_xor(sq, 1);
        float mu = s * 0.01f;
        float var = sq * 0.01f - mu * mu;
        float rs = rsqrtf(var + 1e-5f);
        #pragma unroll
        for (int i = 0; i < 50; ++i)
          hv[i] = (latv[i] - mu) * rs * s_sm[600 + d * 100 + hc + i] + s_sm[800 + d * 100 + hc + i];
      }

      // ---- MLP (MFMA): gelu(h@W1^T+b1)@W2^T + b2, hidden chunks of 128
      __syncthreads();   // s_M region was MHA staging
      #pragma unroll
      for (int i = 0; i < 50; ++i) s_M[r * 136 + hc + i] = f2bf(hv[i]);
      #pragma unroll
      for (int i = 0; i < 14; ++i) s_M[r * 136 + 100 + half * 14 + i] = 0;
      __syncthreads();

      {
        const int w1off = WSB_W1 + d * 51200;
        const int w2off = WSB_W2 + d * 50176;
        f32x4 c2[2][7];
        #pragma unroll
        for (int a0 = 0; a0 < 2; ++a0)
          #pragma unroll
          for (int a1 = 0; a1 < 7; ++a1) c2[a0][a1] = (f32x4){0.f, 0.f, 0.f, 0.f};
        short8 ah[2][4];
        #pragma unroll
        for (int mt2 = 0; mt2 < 2; ++mt2)
          #pragma unroll
          for (int kt = 0; kt < 4; ++kt)
            ah[mt2][kt] = *(const short8*)(s_M + ((2 * wv + mt2) * 16 + li) * 136 + kt * 32 + lg * 8);

        // chunks 0..2: 8 n-tiles (128 hidden) each
        for (int chunk = 0; chunk < 3; ++chunk) {
          f32x4 c1[2][8];
          #pragma unroll
          for (int a0 = 0; a0 < 2; ++a0)
            #pragma unroll
            for (int a1 = 0; a1 < 8; ++a1) c1[a0][a1] = (f32x4){0.f, 0.f, 0.f, 0.f};
          #pragma unroll
          for (int ntl = 0; ntl < 8; ++ntl)
            #pragma unroll
            for (int kt = 0; kt < 4; ++kt) {
              short8 bw = *(const short8*)(wsb + w1off + ((kt * 25 + (chunk * 8 + ntl)) * 64 + lane) * 8);
              #pragma unroll
              for (int mt2 = 0; mt2 < 2; ++mt2) c1[mt2][ntl] = MFMA(ah[mt2][kt], bw, c1[mt2][ntl]);
            }
          // GELU -> s_Hb rows (full 128 cols)
          #pragma unroll
          for (int mt2 = 0; mt2 < 2; ++mt2)
            #pragma unroll
            for (int ntl = 0; ntl < 8; ++ntl) {
              int col = ntl * 16 + li;
              #pragma unroll
              for (int rg = 0; rg < 4; ++rg) {
                int row = (2 * wv + mt2) * 16 + lg * 4 + rg;
                float hval = c1[mt2][ntl][rg] + s_sm[1800 + d * 400 + chunk * 128 + col];
                float ge = 0.5f * hval * (1.0f + erff(hval * 0.70710678118654752f));
                s_Hb[row * 136 + col] = f2bf(ge);
              }
            }
          // GEMM2 partial
          #pragma unroll
          for (int ktl = 0; ktl < 4; ++ktl) {
            short8 ahh[2];
            #pragma unroll
            for (int mt2 = 0; mt2 < 2; ++mt2)
              ahh[mt2] = *(const short8*)(s_Hb + ((2 * wv + mt2) * 16 + li) * 136 + ktl * 32 + lg * 8);
            #pragma unroll
            for (int nt = 0; nt < 7; ++nt) {
              short8 bw = *(const short8*)(wsb + w2off + (((chunk * 4 + ktl) * 7 + nt) * 64 + lane) * 8);
              #pragma unroll
              for (int mt2 = 0; mt2 < 2; ++mt2) c2[mt2][nt] = MFMA(ahh[mt2], bw, c2[mt2][nt]);
            }
          }
        }
        // chunk 3: hidden 384..399 (1 n-tile), then 1 k-step
        {
          f32x4 c1a[2];
          c1a[0] = (f32x4){0.f, 0.f, 0.f, 0.f};
          c1a[1] = (f32x4){0.f, 0.f, 0.f, 0.f};
          #pragma unroll
          for (int kt = 0; kt < 4; ++kt) {
            short8 bw = *(const short8*)(wsb + w1off + ((kt * 25 + 24) * 64 + lane) * 8);
            #pragma unroll
            for (int mt2 = 0; mt2 < 2; ++mt2) c1a[mt2] = MFMA(ah[mt2][kt], bw, c1a[mt2]);
          }
          #pragma unroll
          for (int mt2 = 0; mt2 < 2; ++mt2) {
            int col = li;
            #pragma unroll
            for (int rg = 0; rg < 4; ++rg) {
              int row = (2 * wv + mt2) * 16 + lg * 4 + rg;
              float hval = c1a[mt2][rg] + s_sm[1800 + d * 400 + 384 + col];
              float ge = 0.5f * hval * (1.0f + erff(hval * 0.70710678118654752f));
              s_Hb[row * 136 + col] = f2bf(ge);
            }
          }
          // zero cols 16..127 of own rows
          for (int i = lane; i < 32 * 112; i += 64) {
            int rr = i / 112, cc = 16 + i % 112;
            s_Hb[(32 * wv + rr) * 136 + cc] = 0;
          }
          short8 ahh[2];
          #pragma unroll
          for (int mt2 = 0; mt2 < 2; ++mt2)
            ahh[mt2] = *(const short8*)(s_Hb + ((2 * wv + mt2) * 16 + li) * 136 + lg * 8);
          #pragma unroll
          for (int nt = 0; nt < 7; ++nt) {
            short8 bw = *(const short8*)(wsb + w2off + ((12 * 7 + nt) * 64 + lane) * 8);
            #pragma unroll
            for (int mt2 = 0; mt2 < 2; ++mt2) c2[mt2][nt] = MFMA(ahh[mt2], bw, c2[mt2][nt]);
          }
        }
        __syncthreads();   // done reading s_M/s_Hb -> reuse as s_x
        #pragma unroll
        for (int mt2 = 0; mt2 < 2; ++mt2)
          #pragma unroll
          for (int nt = 0; nt < 7; ++nt) {
            int col = nt * 16 + li;
            if (col < 100) {
              #pragma unroll
              for (int rg = 0; rg < 4; ++rg) {
                int row = (2 * wv + mt2) * 16 + lg * 4 + rg;
                s_x[row * 104 + col] = c2[mt2][nt][rg];
              }
            }
          }
        __syncthreads();
        #pragma unroll
        for (int i = 0; i < 50; ++i) latv[i] += s_x[r * 104 + hc + i] + s_sm[2600 + d * 100 + hc + i];
        __syncthreads();
      }
    }
  }

  //=================== mean over 256 latents ===================
  for (int wd = 128; wd >= 1; wd >>= 1) {
    __syncthreads();
    if (r >= wd && r < 2 * wd) {
      #pragma unroll
      for (int i = 0; i < 50; ++i) reg0[(r - wd) * 100 + hc + i] = latv[i];
    }
    __syncthreads();
    if (r < wd) {
      #pragma unroll
      for (int i = 0; i < 50; ++i) latv[i] += reg0[r * 100 + hc + i];
    }
  }
  if (r == 0) {
    #pragma unroll
    for (int i = 0; i < 50; ++i) out[b * 100 + hc + i] = latv[i] * (1.0f / 256.0f);
  }
}

// ---------------------------------------------------------------------------
extern "C" void kernel_launch(void* const* d_in, const int* in_sizes, int n_in,
                              void* d_out, int out_size, void* d_ws, size_t ws_size,
                              hipStream_t stream) {
  (void)in_sizes; (void)n_in; (void)out_size; (void)ws_size;
  const float* x          = (const float*)d_in[0];
  const float* latents    = (const float*)d_in[1];
  const float* latent_pos = (const float*)d_in[2];
  const float* fm         = (const float*)d_in[3];
  const float* proj_w     = (const float*)d_in[4];
  const float* proj_b     = (const float*)d_in[5];
  const float* q_w        = (const float*)d_in[6];
  const float* q_b        = (const float*)d_in[7];
  const float* k_w        = (const float*)d_in[8];
  const float* k_b        = (const float*)d_in[9];
  const float* v_w        = (const float*)d_in[10];
  const float* v_b        = (const float*)d_in[11];
  const float* o_w        = (const float*)d_in[12];
  const float* o_b        = (const float*)d_in[13];
  const float* ln1_g      = (const float*)d_in[14];
  const float* ln1_b      = (const float*)d_in[15];
  const float* attn_in_w  = (const float*)d_in[16];
  const float* attn_in_b  = (const float*)d_in[17];
  const float* attn_out_w = (const float*)d_in[18];
  const float* attn_out_b = (const float*)d_in[19];
  const float* ln2_g      = (const float*)d_in[20];
  const float* ln2_b      = (const float*)d_in[21];
  const float* mlp_w1     = (const float*)d_in[22];
  const float* mlp_b1     = (const float*)d_in[23];
  const float* mlp_w2     = (const float*)d_in[24];
  const float* mlp_b2     = (const float*)d_in[25];
  float* ws   = (float*)d_ws;
  float* outp = (float*)d_out;
  unsigned short* wsb = (unsigned short*)(ws + WS_BF);

  pre_amat_kernel<<<3, 256, 0, stream>>>(proj_w, k_w, v_w, ws);
  pre_dmat_kernel<<<128, 256, 0, stream>>>(fm, proj_w, proj_b, k_w, k_b, v_w, v_b, ws);
  pre_wfrag_kernel<<<(WSB_TOTAL + 255) / 256, 256, 0, stream>>>(q_w, o_w, mlp_w1, mlp_w2, wsb);
  perceiver_kernel<<<512, 512, 0, stream>>>(
      x, latents, latent_pos, q_b, o_b,
      ln1_g, ln1_b, attn_in_w, attn_in_b, attn_out_w, attn_out_b,
      ln2_g, ln2_b, mlp_b1, mlp_b2, ws, outp);
}

// Round 3
// 6634.212 us; speedup vs baseline: 5.8527x; 3.2275x over previous
//
#include <hip/hip_runtime.h>
#include <cmath>

// float offsets in ws
#define WS_AK 0
#define WS_AV 300
#define WS_U  600   // ushort region starts here (byte offset 2400, 16B aligned)

// ushort offsets relative to uw = (ushort*)(ws + WS_U)
#define UW_DK   0          // bf16 [1024][104]
#define UW_DV   106496     // bf16 [104][1024]  (transposed)
#define UW_QW   212992     // q_w frags  kt4 x nt7
#define UW_OW   227328     // o_w frags  kt4 x nt7
#define UW_W1   241664     // + d*51200  kt4 x nt25
#define UW_W2   344064     // + d*50176  kt14 x nt7
#define UW_AIW  444416     // + (d*3+wsel)*16384  kt4 x nt8 (head-padded n'=h*32+dh)
#define UW_AOW  542720     // + d*14336  kt4 x nt7 (head-padded k'=h*32+dh)
#define UW_WCNT 358400     // elements written by pre_wfrag (from UW_QW)

typedef __attribute__((ext_vector_type(8))) short short8;
typedef __attribute__((ext_vector_type(4))) float f32x4;

#define MFMA(a, b, c) __builtin_amdgcn_mfma_f32_16x16x32_bf16((a), (b), (c), 0, 0, 0)

static __device__ __forceinline__ unsigned short f2bf(float f) {
  unsigned int u = __float_as_uint(f);
  u += 0x7FFF + ((u >> 16) & 1);   // RNE
  return (unsigned short)(u >> 16);
}
static __device__ __forceinline__ float bf2f(unsigned short u) {
  return __uint_as_float(((unsigned int)u) << 16);
}
static __device__ __forceinline__ f32x4 zero4() { return (f32x4){0.f, 0.f, 0.f, 0.f}; }

// ---------------------------------------------------------------------------
// Precompute Ak/Av: Ak[c][m] = sum_n proj_w[n][c] * k_w[m][n]
// ---------------------------------------------------------------------------
__global__ void pre_amat_kernel(const float* __restrict__ proj_w,
                                const float* __restrict__ k_w,
                                const float* __restrict__ v_w,
                                float* __restrict__ ws) {
  int idx = blockIdx.x * blockDim.x + threadIdx.x;
  if (idx >= 600) return;
  int sel = idx / 300;
  int rem = idx % 300;
  int c = rem / 100, m = rem % 100;
  const float* w = sel ? v_w : k_w;
  float acc = 0.f;
  for (int n = 0; n < 100; ++n) acc += proj_w[n * 131 + c] * w[m * 100 + n];
  ws[(sel ? WS_AV : WS_AK) + c * 100 + m] = acc;
}

// ---------------------------------------------------------------------------
// Precompute Dk/Dv (batch-independent part of K/V) -> bf16
// Dk row-major [1024][104] (pads 0); Dv transposed [104][1024]
// ---------------------------------------------------------------------------
__global__ void pre_dmat_kernel(const float* __restrict__ fm,
                                const float* __restrict__ proj_w,
                                const float* __restrict__ proj_b,
                                const float* __restrict__ k_w,
                                const float* __restrict__ k_b,
                                const float* __restrict__ v_w,
                                const float* __restrict__ v_b,
                                unsigned short* __restrict__ uw) {
  __shared__ float pos[8][128];
  __shared__ float tc[8][100];
  int p0 = blockIdx.x * 8;
  int tid = threadIdx.x;
  for (int idx = tid; idx < 1024; idx += 256) {
    int pl = idx >> 7, f = idx & 127;
    int p = p0 + pl;
    float cx = (float)(p & 31) * (1.f / 31.f);
    float cy = (float)(p >> 5) * (1.f / 31.f);
    int fi = f & 63;
    float pr = cx * fm[fi] + cy * fm[64 + fi];
    float ang = 6.2831853071795864769f * pr;
    pos[pl][f] = (f < 64) ? cosf(ang) : sinf(ang);
  }
  __syncthreads();
  for (int idx = tid; idx < 800; idx += 256) {
    int pl = idx / 100, n = idx % 100;
    float acc = proj_b[n];
    const float* pw = proj_w + n * 131 + 3;
    for (int f = 0; f < 128; ++f) acc += pos[pl][f] * pw[f];
    tc[pl][n] = acc;
  }
  __syncthreads();
  for (int idx = tid; idx < 1600; idx += 256) {
    int sel = idx / 800;
    int rem = idx % 800;
    int pl = rem / 100, m = rem % 100;
    const float* w = sel ? v_w : k_w;
    float acc = sel ? v_b[m] : k_b[m];
    for (int n = 0; n < 100; ++n) acc += tc[pl][n] * w[m * 100 + n];
    if (sel) uw[UW_DV + m * 1024 + (p0 + pl)] = f2bf(acc);
    else     uw[UW_DK + (p0 + pl) * 104 + m] = f2bf(acc);
  }
  for (int idx = tid; idx < 32; idx += 256) {
    int pl = idx >> 2, mm = 100 + (idx & 3);
    uw[UW_DK + (p0 + pl) * 104 + mm] = 0;
  }
}

// ---------------------------------------------------------------------------
// Pre-convert all GEMM weights to bf16 B-fragment-linear layouts.
// Frag addr = ((kt*NT + nt)*64 + lane)*8 + j ; k = kt*32+(lane>>4)*8+j ;
// n = nt*16+(lane&15).
// ---------------------------------------------------------------------------
__global__ void pre_wfrag_kernel(const float* __restrict__ q_w,
                                 const float* __restrict__ o_w,
                                 const float* __restrict__ mlp_w1,
                                 const float* __restrict__ mlp_w2,
                                 const float* __restrict__ attn_in_w,
                                 const float* __restrict__ attn_out_w,
                                 unsigned short* __restrict__ uw) {
  int idx = blockIdx.x * 256 + threadIdx.x;
  if (idx >= UW_WCNT) return;
  float val = 0.f;
  if (idx < 14336) {                       // QW
    int rem = idx;
    int kt = rem / 3584; rem %= 3584;
    int nt = rem / 512;  rem %= 512;
    int lane = rem >> 3, j = rem & 7;
    int k = kt * 32 + (lane >> 4) * 8 + j;
    int n = nt * 16 + (lane & 15);
    if (k < 100 && n < 100) val = q_w[n * 100 + k];
  } else if (idx < 28672) {                // OW
    int rem = idx - 14336;
    int kt = rem / 3584; rem %= 3584;
    int nt = rem / 512;  rem %= 512;
    int lane = rem >> 3, j = rem & 7;
    int k = kt * 32 + (lane >> 4) * 8 + j;
    int n = nt * 16 + (lane & 15);
    if (k < 100 && n < 100) val = o_w[n * 100 + k];
  } else if (idx < 131072) {               // W1[d]
    int off = idx - 28672;
    int dd = off / 51200;
    int rem = off % 51200;
    int kt = rem / 12800; rem %= 12800;
    int nt = rem / 512;   rem %= 512;
    int lane = rem >> 3, j = rem & 7;
    int k = kt * 32 + (lane >> 4) * 8 + j;
    int n = nt * 16 + (lane & 15);
    if (k < 100) val = mlp_w1[dd * 40000 + n * 100 + k];
  } else if (idx < 231424) {               // W2[d]
    int off = idx - 131072;
    int dd = off / 50176;
    int rem = off % 50176;
    int kt = rem / 3584; rem %= 3584;
    int nt = rem / 512;  rem %= 512;
    int lane = rem >> 3, j = rem & 7;
    int k = kt * 32 + (lane >> 4) * 8 + j;
    int n = nt * 16 + (lane & 15);
    if (k < 400 && n < 100) val = mlp_w2[dd * 40000 + n * 400 + k];
  } else if (idx < 329728) {               // AIW[d][wsel], head-padded n'
    int off = idx - 231424;
    int dw = off / 16384;
    int rem = off % 16384;
    int dd = dw / 3, wsel = dw % 3;
    int kt = rem / 4096; rem %= 4096;
    int nt = rem / 512;  rem %= 512;
    int lane = rem >> 3, j = rem & 7;
    int k = kt * 32 + (lane >> 4) * 8 + j;
    int np = nt * 16 + (lane & 15);
    int hh = np >> 5, dh = np & 31;
    if (k < 100 && dh < 25)
      val = attn_in_w[dd * 30000 + (wsel * 100 + hh * 25 + dh) * 100 + k];
  } else {                                  // AOW[d], head-padded k'
    int off = idx - 329728;
    int dd = off / 14336;
    int rem = off % 14336;
    int kt = rem / 3584; rem %= 3584;
    int nt = rem / 512;  rem %= 512;
    int lane = rem >> 3, j = rem & 7;
    int kp = kt * 32 + (lane >> 4) * 8 + j;
    int hh = kp >> 5, dh = kp & 31;
    int n = nt * 16 + (lane & 15);
    if (dh < 25 && n < 100)
      val = attn_out_w[dd * 10000 + n * 100 + hh * 25 + dh];
  }
  uw[UW_QW + idx] = f2bf(val);
}

// ---------------------------------------------------------------------------
// Main fused kernel: one block per batch item, 512 threads (8 waves).
// Wave w owns latent rows [32w, 32w+32) (m-tiles 2w, 2w+1).
// Pair (2r,2r+1): thread (r,half) holds lat[r][half*50..+50) f32 in registers.
// ---------------------------------------------------------------------------
__launch_bounds__(512, 1)
__global__ void perceiver_kernel(
    const float* __restrict__ x,
    const float* __restrict__ latents,
    const float* __restrict__ latent_pos,
    const float* __restrict__ q_b, const float* __restrict__ o_b,
    const float* __restrict__ ln1_g, const float* __restrict__ ln1_b,
    const float* __restrict__ attn_in_b, const float* __restrict__ attn_out_b,
    const float* __restrict__ ln2_g, const float* __restrict__ ln2_b,
    const float* __restrict__ mlp_b1, const float* __restrict__ mlp_b2,
    const float* __restrict__ ws,
    float* __restrict__ out) {
  __shared__ __align__(16) float s_pool[39240];
  float* s_sm = s_pool;
  float* reg0 = s_pool + 3400;
  unsigned short* s_M  = (unsigned short*)reg0;             // [256][136] bf16
  unsigned short* s_Hb = (unsigned short*)(reg0 + 17408);   // 36864 ushorts
  // cross-attn aliases
  unsigned short* sK = s_Hb;                                 // [16][64][8]
  unsigned short* sV = s_Hb + 8192;                          // [8][112][8]
  unsigned short* sP = s_Hb + 15360;                         // [256][72]
  // MHA aliases
  unsigned short* s_Qh  = s_Hb;                              // [256][40]
  unsigned short* kfrag = s_Hb + 10240;                      // [16nt][64][8]
  unsigned short* vfrag = s_Hb + 18432;                      // [16][64][8]
  unsigned short* sPm   = s_Hb + 26624;                      // [256][40]
  float* s_x = reg0;                                         // [256][104] f32

  const int tid  = threadIdx.x;
  const int b    = blockIdx.x;
  const int r    = tid >> 1;
  const int half = tid & 1;
  const int hc   = half * 50;
  const int lane = tid & 63;
  const int wv   = tid >> 6;
  const int li   = lane & 15;
  const int lg   = lane >> 4;
  const unsigned short* uw = (const unsigned short*)(ws + WS_U);

  // ---- stage small constants ----
  for (int i = tid; i < 100; i += 512) { s_sm[i] = q_b[i]; s_sm[100 + i] = o_b[i]; }
  for (int i = tid; i < 200; i += 512) {
    s_sm[200 + i] = ln1_g[i]; s_sm[400 + i] = ln1_b[i];
    s_sm[600 + i] = ln2_g[i]; s_sm[800 + i] = ln2_b[i];
    s_sm[1600 + i] = attn_out_b[i]; s_sm[2600 + i] = mlp_b2[i];
  }
  for (int i = tid; i < 600; i += 512) s_sm[1000 + i] = attn_in_b[i];
  for (int i = tid; i < 800; i += 512) s_sm[1800 + i] = mlp_b1[i];
  for (int i = tid; i < 300; i += 512) { s_sm[2800 + i] = ws[WS_AK + i]; s_sm[3100 + i] = ws[WS_AV + i]; }

  float latv[50];
  #pragma unroll
  for (int i = 0; i < 50; ++i)
    latv[i] = latents[r * 100 + hc + i] + latent_pos[r * 100 + hc + i];

  const float* xb = x + (long)b * 3072;

  for (int it = 0; it < 8; ++it) {
    //=================== cross attention (MFMA) ===================
    __syncthreads();
    #pragma unroll
    for (int i = 0; i < 50; ++i) s_M[r * 136 + hc + i] = f2bf(latv[i]);
    #pragma unroll
    for (int i = 0; i < 14; ++i) s_M[r * 136 + 100 + half * 14 + i] = 0;
    __syncthreads();

    // ---- q-proj: q = (lat @ q_w^T + q_b) * 0.1 -> s_M (overwrite)
    {
      f32x4 qacc[2][7];
      #pragma unroll
      for (int a0 = 0; a0 < 2; ++a0)
        #pragma unroll
        for (int a1 = 0; a1 < 7; ++a1) qacc[a0][a1] = zero4();
      short8 aq[2][4];
      #pragma unroll
      for (int mt2 = 0; mt2 < 2; ++mt2)
        #pragma unroll
        for (int kt = 0; kt < 4; ++kt)
          aq[mt2][kt] = *(const short8*)(s_M + ((2 * wv + mt2) * 16 + li) * 136 + kt * 32 + lg * 8);
      #pragma unroll
      for (int nt = 0; nt < 7; ++nt)
        #pragma unroll
        for (int kt = 0; kt < 4; ++kt) {
          short8 bw = *(const short8*)(uw + UW_QW + ((kt * 7 + nt) * 64 + lane) * 8);
          #pragma unroll
          for (int mt2 = 0; mt2 < 2; ++mt2) qacc[mt2][nt] = MFMA(aq[mt2][kt], bw, qacc[mt2][nt]);
        }
      #pragma unroll
      for (int mt2 = 0; mt2 < 2; ++mt2)
        #pragma unroll
        for (int nt = 0; nt < 7; ++nt) {
          int col = nt * 16 + li;
          if (col < 100) {
            #pragma unroll
            for (int rg = 0; rg < 4; ++rg) {
              int row = (2 * wv + mt2) * 16 + lg * 4 + rg;
              s_M[row * 136 + col] = f2bf((qacc[mt2][nt][rg] + s_sm[col]) * 0.1f);
            }
          }
        }
    }

    // ---- attention: O = exp(q@K^T) @ [V|1]
    f32x4 O[2][7];
    #pragma unroll
    for (int a0 = 0; a0 < 2; ++a0)
      #pragma unroll
      for (int a1 = 0; a1 < 7; ++a1) O[a0][a1] = zero4();
    short8 aq2[2][4];
    #pragma unroll
    for (int mt2 = 0; mt2 < 2; ++mt2)
      #pragma unroll
      for (int kt = 0; kt < 4; ++kt)
        aq2[mt2][kt] = *(const short8*)(s_M + ((2 * wv + mt2) * 16 + li) * 136 + kt * 32 + lg * 8);

    for (int t0 = 0; t0 < 1024; t0 += 64) {
      __syncthreads();
      // K-tile: sK[(cg*64+key)*8 + j], c = cg*8+j
      for (int vi = tid; vi < 1024; vi += 512) {
        const int key = vi & 63, cg = vi >> 6;
        const int p = t0 + key;
        short8 w;
        if (cg < 13) {
          const float xr = xb[p], xg = xb[1024 + p], xv = xb[2048 + p];
          short8 dk = *(const short8*)(uw + UW_DK + p * 104 + cg * 8);
          #pragma unroll
          for (int e = 0; e < 8; ++e) {
            const int c = cg * 8 + e;
            float val = 0.f;
            if (c < 100)
              val = xr * s_sm[2800 + c] + xg * s_sm[2900 + c] + xv * s_sm[3000 + c]
                  + bf2f((unsigned short)w[0] * 0 + (unsigned short)dk[e]);
            w[e] = (short)f2bf(val);
          }
        } else {
          #pragma unroll
          for (int e = 0; e < 8; ++e) w[e] = 0;
        }
        *(short8*)(sK + vi * 8) = w;
      }
      // V-tile: sV[(kg*112+ch)*8 + j], key = kg*8+j; ch 100 = ones col
      for (int vi = tid; vi < 896; vi += 512) {
        const int ch = vi % 112, kg = vi / 112;
        const int pv0 = t0 + kg * 8;
        short8 w;
        if (ch < 100) {
          const float4 xr0 = *(const float4*)(xb + pv0);
          const float4 xr1 = *(const float4*)(xb + pv0 + 4);
          const float4 xg0 = *(const float4*)(xb + 1024 + pv0);
          const float4 xg1 = *(const float4*)(xb + 1024 + pv0 + 4);
          const float4 xv0 = *(const float4*)(xb + 2048 + pv0);
          const float4 xv1 = *(const float4*)(xb + 2048 + pv0 + 4);
          short8 dv = *(const short8*)(uw + UW_DV + ch * 1024 + pv0);
          const float a0 = s_sm[3100 + ch], a1 = s_sm[3200 + ch], a2 = s_sm[3300 + ch];
          const float xrv[8] = {xr0.x, xr0.y, xr0.z, xr0.w, xr1.x, xr1.y, xr1.z, xr1.w};
          const float xgv[8] = {xg0.x, xg0.y, xg0.z, xg0.w, xg1.x, xg1.y, xg1.z, xg1.w};
          const float xvv[8] = {xv0.x, xv0.y, xv0.z, xv0.w, xv1.x, xv1.y, xv1.z, xv1.w};
          #pragma unroll
          for (int e = 0; e < 8; ++e)
            w[e] = (short)f2bf(xrv[e] * a0 + xgv[e] * a1 + xvv[e] * a2
                               + bf2f((unsigned short)dv[e]));
        } else if (ch == 100) {
          #pragma unroll
          for (int e = 0; e < 8; ++e) w[e] = (short)0x3F80;   // bf16 1.0
        } else {
          #pragma unroll
          for (int e = 0; e < 8; ++e) w[e] = 0;
        }
        *(short8*)(sV + vi * 8) = w;
      }
      __syncthreads();

      // S-GEMM + exp -> sP
      #pragma unroll
      for (int ntk = 0; ntk < 4; ++ntk) {
        short8 bk[4];
        #pragma unroll
        for (int kt = 0; kt < 4; ++kt)
          bk[kt] = *(const short8*)(sK + ((kt * 4 + lg) * 64 + ntk * 16 + li) * 8);
        #pragma unroll
        for (int mt2 = 0; mt2 < 2; ++mt2) {
          f32x4 sres = zero4();
          #pragma unroll
          for (int kt = 0; kt < 4; ++kt) sres = MFMA(aq2[mt2][kt], bk[kt], sres);
          #pragma unroll
          for (int rg = 0; rg < 4; ++rg) {
            int row = (2 * wv + mt2) * 16 + lg * 4 + rg;
            sP[row * 72 + ntk * 16 + li] = f2bf(__expf(sres[rg]));
          }
        }
      }
      // PV accumulate
      short8 ap[2][2];
      #pragma unroll
      for (int mt2 = 0; mt2 < 2; ++mt2)
        #pragma unroll
        for (int kt2 = 0; kt2 < 2; ++kt2)
          ap[mt2][kt2] = *(const short8*)(sP + ((2 * wv + mt2) * 16 + li) * 72 + kt2 * 32 + lg * 8);
      #pragma unroll
      for (int nt = 0; nt < 7; ++nt) {
        short8 bv0 = *(const short8*)(sV + ((0 + lg) * 112 + nt * 16 + li) * 8);
        short8 bv1 = *(const short8*)(sV + ((4 + lg) * 112 + nt * 16 + li) * 8);
        #pragma unroll
        for (int mt2 = 0; mt2 < 2; ++mt2) {
          O[mt2][nt] = MFMA(ap[mt2][0], bv0, O[mt2][nt]);
          O[mt2][nt] = MFMA(ap[mt2][1], bv1, O[mt2][nt]);
        }
      }
    }

    // ---- normalize (l at col 100 -> nt=6, li==4), write o_in -> s_M
    {
      #pragma unroll
      for (int mt2 = 0; mt2 < 2; ++mt2) {
        float linv[4];
        #pragma unroll
        for (int rg = 0; rg < 4; ++rg) {
          float lv = __shfl(O[mt2][6][rg], (lane & 48) + 4);
          linv[rg] = 1.0f / lv;
        }
        #pragma unroll
        for (int nt = 0; nt < 7; ++nt) {
          int col = nt * 16 + li;
          if (col < 100) {
            #pragma unroll
            for (int rg = 0; rg < 4; ++rg) {
              int row = (2 * wv + mt2) * 16 + lg * 4 + rg;
              s_M[row * 136 + col] = f2bf(O[mt2][nt][rg] * linv[rg]);
            }
          }
        }
      }
    }

    // ---- o-proj: lat' = o_in @ o_w^T + o_b -> s_x -> latv
    {
      f32x4 lacc[2][7];
      #pragma unroll
      for (int a0 = 0; a0 < 2; ++a0)
        #pragma unroll
        for (int a1 = 0; a1 < 7; ++a1) lacc[a0][a1] = zero4();
      short8 ao[2][4];
      #pragma unroll
      for (int mt2 = 0; mt2 < 2; ++mt2)
        #pragma unroll
        for (int kt = 0; kt < 4; ++kt)
          ao[mt2][kt] = *(const short8*)(s_M + ((2 * wv + mt2) * 16 + li) * 136 + kt * 32 + lg * 8);
      #pragma unroll
      for (int nt = 0; nt < 7; ++nt)
        #pragma unroll
        for (int kt = 0; kt < 4; ++kt) {
          short8 bw = *(const short8*)(uw + UW_OW + ((kt * 7 + nt) * 64 + lane) * 8);
          #pragma unroll
          for (int mt2 = 0; mt2 < 2; ++mt2) lacc[mt2][nt] = MFMA(ao[mt2][kt], bw, lacc[mt2][nt]);
        }
      __syncthreads();
      #pragma unroll
      for (int mt2 = 0; mt2 < 2; ++mt2)
        #pragma unroll
        for (int nt = 0; nt < 7; ++nt) {
          int col = nt * 16 + li;
          if (col < 100) {
            #pragma unroll
            for (int rg = 0; rg < 4; ++rg) {
              int row = (2 * wv + mt2) * 16 + lg * 4 + rg;
              s_x[row * 104 + col] = lacc[mt2][nt][rg] + s_sm[100 + col];
            }
          }
        }
      __syncthreads();
      #pragma unroll
      for (int i = 0; i < 50; ++i) latv[i] = s_x[r * 104 + hc + i];
      __syncthreads();
    }

    //=================== latent transformer ===================
    for (int d = 0; d < 2; ++d) {
      // ---- LN1 -> hv
      float hv[50];
      {
        float s = 0.f, sq = 0.f;
        #pragma unroll
        for (int i = 0; i < 50; ++i) { s += latv[i]; sq += latv[i] * latv[i]; }
        s += __shfl_xor(s, 1); sq += __shfl_xor(sq, 1);
        float mu = s * 0.01f;
        float var = sq * 0.01f - mu * mu;
        float rs = rsqrtf(var + 1e-5f);
        #pragma unroll
        for (int i = 0; i < 50; ++i)
          hv[i] = (latv[i] - mu) * rs * s_sm[200 + d * 100 + hc + i] + s_sm[400 + d * 100 + hc + i];
      }

      // ---- MHA (MFMA): per-head QKV GEMM + no-max softmax + PV + out-proj
      #pragma unroll
      for (int i = 0; i < 50; ++i) s_M[r * 136 + hc + i] = f2bf(hv[i]);
      #pragma unroll
      for (int i = 0; i < 14; ++i) s_M[r * 136 + 100 + half * 14 + i] = 0;
      short8 ah[2][4];
      #pragma unroll
      for (int mt2 = 0; mt2 < 2; ++mt2)
        #pragma unroll
        for (int kt = 0; kt < 4; ++kt)
          ah[mt2][kt] = *(const short8*)(s_M + ((2 * wv + mt2) * 16 + li) * 136 + kt * 32 + lg * 8);

      for (int h = 0; h < 4; ++h) {
        __syncthreads();   // prev head's kfrag/vfrag reads done (or prev-phase s_Hb use)
        // --- Q/K/V GEMMs for own 32 rows
        f32x4 cq[2][2], ck[2][2], cv[2][2];
        #pragma unroll
        for (int a0 = 0; a0 < 2; ++a0)
          #pragma unroll
          for (int a1 = 0; a1 < 2; ++a1) { cq[a0][a1] = zero4(); ck[a0][a1] = zero4(); cv[a0][a1] = zero4(); }
        #pragma unroll
        for (int ntd = 0; ntd < 2; ++ntd)
          #pragma unroll
          for (int kt = 0; kt < 4; ++kt) {
            const int bidx = ((kt * 8 + h * 2 + ntd) * 64 + lane) * 8;
            short8 bq  = *(const short8*)(uw + UW_AIW + (d * 3 + 0) * 16384 + bidx);
            short8 bkk = *(const short8*)(uw + UW_AIW + (d * 3 + 1) * 16384 + bidx);
            short8 bvv = *(const short8*)(uw + UW_AIW + (d * 3 + 2) * 16384 + bidx);
            #pragma unroll
            for (int mt2 = 0; mt2 < 2; ++mt2) {
              cq[mt2][ntd] = MFMA(ah[mt2][kt], bq,  cq[mt2][ntd]);
              ck[mt2][ntd] = MFMA(ah[mt2][kt], bkk, ck[mt2][ntd]);
              cv[mt2][ntd] = MFMA(ah[mt2][kt], bvv, cv[mt2][ntd]);
            }
          }
        // --- epilogue: Qh rows + kfrag/vfrag scatter (bias, pad, ones col)
        #pragma unroll
        for (int mt2 = 0; mt2 < 2; ++mt2)
          #pragma unroll
          for (int ntd = 0; ntd < 2; ++ntd) {
            const int dh = ntd * 16 + li;
            const bool ok = dh < 25;
            const float qb2 = ok ? s_sm[1000 + d * 300 +       h * 25 + dh] : 0.f;
            const float kb2 = ok ? s_sm[1000 + d * 300 + 100 + h * 25 + dh] : 0.f;
            const float vb2 = ok ? s_sm[1000 + d * 300 + 200 + h * 25 + dh] : 0.f;
            #pragma unroll
            for (int rg = 0; rg < 4; ++rg) {
              const int rr = lg * 4 + rg;
              const int row = (2 * wv + mt2) * 16 + rr;
              s_Qh[row * 40 + dh] = ok ? f2bf((cq[mt2][ntd][rg] + qb2) * 0.2f) : 0;
              kfrag[((2 * wv + mt2) * 64 + (dh >> 3) * 16 + rr) * 8 + (dh & 7)] =
                  ok ? f2bf(ck[mt2][ntd][rg] + kb2) : 0;
              vfrag[((wv * 2 + ntd) * 64 + (mt2 * 2 + (rr >> 3)) * 16 + li) * 8 + (rr & 7)] =
                  ok ? f2bf(cv[mt2][ntd][rg] + vb2)
                     : (unsigned short)((dh == 25) ? 0x3F80 : 0);
            }
          }
        __syncthreads();   // kfrag/vfrag visible to all waves
        // --- S + PV over 8 key-tiles (wave-local: Qh/sPm rows are private)
        short8 aqh[2];
        #pragma unroll
        for (int mt2 = 0; mt2 < 2; ++mt2)
          aqh[mt2] = *(const short8*)(s_Qh + ((2 * wv + mt2) * 16 + li) * 40 + lg * 8);
        f32x4 Oh[2][2];
        #pragma unroll
        for (int a0 = 0; a0 < 2; ++a0)
          #pragma unroll
          for (int a1 = 0; a1 < 2; ++a1) Oh[a0][a1] = zero4();
        for (int t = 0; t < 8; ++t) {
          short8 bk0 = *(const short8*)(kfrag + ((t * 2 + 0) * 64 + lane) * 8);
          short8 bk1 = *(const short8*)(kfrag + ((t * 2 + 1) * 64 + lane) * 8);
          f32x4 sres[2][2];
          #pragma unroll
          for (int mt2 = 0; mt2 < 2; ++mt2) {
            sres[mt2][0] = MFMA(aqh[mt2], bk0, zero4());
            sres[mt2][1] = MFMA(aqh[mt2], bk1, zero4());
          }
          #pragma unroll
          for (int mt2 = 0; mt2 < 2; ++mt2)
            #pragma unroll
            for (int ntk = 0; ntk < 2; ++ntk)
              #pragma unroll
              for (int rg = 0; rg < 4; ++rg) {
                const int row = (2 * wv + mt2) * 16 + lg * 4 + rg;
                sPm[row * 40 + ntk * 16 + li] = f2bf(__expf(sres[mt2][ntk][rg]));
              }
          short8 ap0 = *(const short8*)(sPm + ((2 * wv + 0) * 16 + li) * 40 + lg * 8);
          short8 ap1 = *(const short8*)(sPm + ((2 * wv + 1) * 16 + li) * 40 + lg * 8);
          short8 bv0 = *(const short8*)(vfrag + ((t * 2 + 0) * 64 + lane) * 8);
          short8 bv1 = *(const short8*)(vfrag + ((t * 2 + 1) * 64 + lane) * 8);
          Oh[0][0] = MFMA(ap0, bv0, Oh[0][0]);
          Oh[0][1] = MFMA(ap0, bv1, Oh[0][1]);
          Oh[1][0] = MFMA(ap1, bv0, Oh[1][0]);
          Oh[1][1] = MFMA(ap1, bv1, Oh[1][1]);
        }
        // --- normalize (l at dh=25: ntv=1, li==9) and write O_h -> s_M
        #pragma unroll
        for (int mt2 = 0; mt2 < 2; ++mt2)
          #pragma unroll
          for (int rg = 0; rg < 4; ++rg) {
            const float lv = __shfl(Oh[mt2][1][rg], (lane & 48) + 9);
            const float linv = 1.0f / lv;
            #pragma unroll
            for (int ntv = 0; ntv < 2; ++ntv) {
              const int dh = ntv * 16 + li;
              const int row = (2 * wv + mt2) * 16 + lg * 4 + rg;
              s_M[row * 136 + h * 32 + dh] =
                  (dh < 25) ? f2bf(Oh[mt2][ntv][rg] * linv) : 0;
            }
          }
      }
      __syncthreads();   // all waves done with kfrag/vfrag before s_x overwrite
      // --- out-proj: lat += O @ out_w^T + out_b
      {
        short8 ao[2][4];
        #pragma unroll
        for (int mt2 = 0; mt2 < 2; ++mt2)
          #pragma unroll
          for (int kt = 0; kt < 4; ++kt)
            ao[mt2][kt] = *(const short8*)(s_M + ((2 * wv + mt2) * 16 + li) * 136 + kt * 32 + lg * 8);
        __syncthreads();   // ao loads done before s_x overwrites other waves' s_M rows
        f32x4 co[2][7];
        #pragma unroll
        for (int a0 = 0; a0 < 2; ++a0)
          #pragma unroll
          for (int a1 = 0; a1 < 7; ++a1) co[a0][a1] = zero4();
        #pragma unroll
        for (int nt = 0; nt < 7; ++nt)
          #pragma unroll
          for (int kt = 0; kt < 4; ++kt) {
            short8 bw = *(const short8*)(uw + UW_AOW + d * 14336 + ((kt * 7 + nt) * 64 + lane) * 8);
            #pragma unroll
            for (int mt2 = 0; mt2 < 2; ++mt2) co[mt2][nt] = MFMA(ao[mt2][kt], bw, co[mt2][nt]);
          }
        #pragma unroll
        for (int mt2 = 0; mt2 < 2; ++mt2)
          #pragma unroll
          for (int nt = 0; nt < 7; ++nt) {
            const int col = nt * 16 + li;
            if (col < 100) {
              #pragma unroll
              for (int rg = 0; rg < 4; ++rg) {
                const int row = (2 * wv + mt2) * 16 + lg * 4 + rg;
                s_x[row * 104 + col] = co[mt2][nt][rg] + s_sm[1600 + d * 100 + col];
              }
            }
          }
        #pragma unroll
        for (int i = 0; i < 50; ++i) latv[i] += s_x[r * 104 + hc + i];
      }

      // ---- LN2 -> hv
      {
        float s = 0.f, sq = 0.f;
        #pragma unroll
        for (int i = 0; i < 50; ++i) { s += latv[i]; sq += latv[i] * latv[i]; }
        s += __shfl_xor(s, 1); sq += __shfl_xor(sq, 1);
        float mu = s * 0.01f;
        float var = sq * 0.01f - mu * mu;
        float rs = rsqrtf(var + 1e-5f);
        #pragma unroll
        for (int i = 0; i < 50; ++i)
          hv[i] = (latv[i] - mu) * rs * s_sm[600 + d * 100 + hc + i] + s_sm[800 + d * 100 + hc + i];
      }

      // ---- MLP (MFMA)
      __syncthreads();   // all s_x reads done before s_M/s_Hb overwrite
      #pragma unroll
      for (int i = 0; i < 50; ++i) s_M[r * 136 + hc + i] = f2bf(hv[i]);
      #pragma unroll
      for (int i = 0; i < 14; ++i) s_M[r * 136 + 100 + half * 14 + i] = 0;
      __syncthreads();

      {
        const int w1off = UW_W1 + d * 51200;
        const int w2off = UW_W2 + d * 50176;
        f32x4 c2[2][7];
        #pragma unroll
        for (int a0 = 0; a0 < 2; ++a0)
          #pragma unroll
          for (int a1 = 0; a1 < 7; ++a1) c2[a0][a1] = zero4();
        short8 ahm[2][4];
        #pragma unroll
        for (int mt2 = 0; mt2 < 2; ++mt2)
          #pragma unroll
          for (int kt = 0; kt < 4; ++kt)
            ahm[mt2][kt] = *(const short8*)(s_M + ((2 * wv + mt2) * 16 + li) * 136 + kt * 32 + lg * 8);

        for (int chunk = 0; chunk < 3; ++chunk) {
          f32x4 c1[2][8];
          #pragma unroll
          for (int a0 = 0; a0 < 2; ++a0)
            #pragma unroll
            for (int a1 = 0; a1 < 8; ++a1) c1[a0][a1] = zero4();
          #pragma unroll
          for (int ntl = 0; ntl < 8; ++ntl)
            #pragma unroll
            for (int kt = 0; kt < 4; ++kt) {
              short8 bw = *(const short8*)(uw + w1off + ((kt * 25 + (chunk * 8 + ntl)) * 64 + lane) * 8);
              #pragma unroll
              for (int mt2 = 0; mt2 < 2; ++mt2) c1[mt2][ntl] = MFMA(ahm[mt2][kt], bw, c1[mt2][ntl]);
            }
          #pragma unroll
          for (int mt2 = 0; mt2 < 2; ++mt2)
            #pragma unroll
            for (int ntl = 0; ntl < 8; ++ntl) {
              int col = ntl * 16 + li;
              #pragma unroll
              for (int rg = 0; rg < 4; ++rg) {
                int row = (2 * wv + mt2) * 16 + lg * 4 + rg;
                float hval = c1[mt2][ntl][rg] + s_sm[1800 + d * 400 + chunk * 128 + col];
                float ge = 0.5f * hval * (1.0f + erff(hval * 0.70710678118654752f));
                s_Hb[row * 136 + col] = f2bf(ge);
              }
            }
          #pragma unroll
          for (int ktl = 0; ktl < 4; ++ktl) {
            short8 ahh[2];
            #pragma unroll
            for (int mt2 = 0; mt2 < 2; ++mt2)
              ahh[mt2] = *(const short8*)(s_Hb + ((2 * wv + mt2) * 16 + li) * 136 + ktl * 32 + lg * 8);
            #pragma unroll
            for (int nt = 0; nt < 7; ++nt) {
              short8 bw = *(const short8*)(uw + w2off + (((chunk * 4 + ktl) * 7 + nt) * 64 + lane) * 8);
              #pragma unroll
              for (int mt2 = 0; mt2 < 2; ++mt2) c2[mt2][nt] = MFMA(ahh[mt2], bw, c2[mt2][nt]);
            }
          }
        }
        {
          f32x4 c1a[2];
          c1a[0] = zero4(); c1a[1] = zero4();
          #pragma unroll
          for (int kt = 0; kt < 4; ++kt) {
            short8 bw = *(const short8*)(uw + w1off + ((kt * 25 + 24) * 64 + lane) * 8);
            #pragma unroll
            for (int mt2 = 0; mt2 < 2; ++mt2) c1a[mt2] = MFMA(ahm[mt2][kt], bw, c1a[mt2]);
          }
          #pragma unroll
          for (int mt2 = 0; mt2 < 2; ++mt2) {
            int col = li;
            #pragma unroll
            for (int rg = 0; rg < 4; ++rg) {
              int row = (2 * wv + mt2) * 16 + lg * 4 + rg;
              float hval = c1a[mt2][rg] + s_sm[1800 + d * 400 + 384 + col];
              float ge = 0.5f * hval * (1.0f + erff(hval * 0.70710678118654752f));
              s_Hb[row * 136 + col] = f2bf(ge);
            }
          }
          for (int i = lane; i < 32 * 112; i += 64) {
            int rr2 = i / 112, cc = 16 + i % 112;
            s_Hb[(32 * wv + rr2) * 136 + cc] = 0;
          }
          short8 ahh[2];
          #pragma unroll
          for (int mt2 = 0; mt2 < 2; ++mt2)
            ahh[mt2] = *(const short8*)(s_Hb + ((2 * wv + mt2) * 16 + li) * 136 + lg * 8);
          #pragma unroll
          for (int nt = 0; nt < 7; ++nt) {
            short8 bw = *(const short8*)(uw + w2off + ((12 * 7 + nt) * 64 + lane) * 8);
            #pragma unroll
            for (int mt2 = 0; mt2 < 2; ++mt2) c2[mt2][nt] = MFMA(ahh[mt2], bw, c2[mt2][nt]);
          }
        }
        __syncthreads();
        #pragma unroll
        for (int mt2 = 0; mt2 < 2; ++mt2)
          #pragma unroll
          for (int nt = 0; nt < 7; ++nt) {
            int col = nt * 16 + li;
            if (col < 100) {
              #pragma unroll
              for (int rg = 0; rg < 4; ++rg) {
                int row = (2 * wv + mt2) * 16 + lg * 4 + rg;
                s_x[row * 104 + col] = c2[mt2][nt][rg];
              }
            }
          }
        __syncthreads();
        #pragma unroll
        for (int i = 0; i < 50; ++i) latv[i] += s_x[r * 104 + hc + i] + s_sm[2600 + d * 100 + hc + i];
        __syncthreads();
      }
    }
  }

  //=================== mean over 256 latents ===================
  for (int wd = 128; wd >= 1; wd >>= 1) {
    __syncthreads();
    if (r >= wd && r < 2 * wd) {
      #pragma unroll
      for (int i = 0; i < 50; ++i) reg0[(r - wd) * 100 + hc + i] = latv[i];
    }
    __syncthreads();
    if (r < wd) {
      #pragma unroll
      for (int i = 0; i < 50; ++i) latv[i] += reg0[r * 100 + hc + i];
    }
  }
  if (r == 0) {
    #pragma unroll
    for (int i = 0; i < 50; ++i) out[b * 100 + hc + i] = latv[i] * (1.0f / 256.0f);
  }
}

// ---------------------------------------------------------------------------
extern "C" void kernel_launch(void* const* d_in, const int* in_sizes, int n_in,
                              void* d_out, int out_size, void* d_ws, size_t ws_size,
                              hipStream_t stream) {
  (void)in_sizes; (void)n_in; (void)out_size; (void)ws_size;
  const float* x          = (const float*)d_in[0];
  const float* latents    = (const float*)d_in[1];
  const float* latent_pos = (const float*)d_in[2];
  const float* fm         = (const float*)d_in[3];
  const float* proj_w     = (const float*)d_in[4];
  const float* proj_b     = (const float*)d_in[5];
  const float* q_w        = (const float*)d_in[6];
  const float* q_b        = (const float*)d_in[7];
  const float* k_w        = (const float*)d_in[8];
  const float* k_b        = (const float*)d_in[9];
  const float* v_w        = (const float*)d_in[10];
  const float* v_b        = (const float*)d_in[11];
  const float* o_w        = (const float*)d_in[12];
  const float* o_b        = (const float*)d_in[13];
  const float* ln1_g      = (const float*)d_in[14];
  const float* ln1_b      = (const float*)d_in[15];
  const float* attn_in_w  = (const float*)d_in[16];
  const float* attn_in_b  = (const float*)d_in[17];
  const float* attn_out_w = (const float*)d_in[18];
  const float* attn_out_b = (const float*)d_in[19];
  const float* ln2_g      = (const float*)d_in[20];
  const float* ln2_b      = (const float*)d_in[21];
  const float* mlp_w1     = (const float*)d_in[22];
  const float* mlp_b1     = (const float*)d_in[23];
  const float* mlp_w2     = (const float*)d_in[24];
  const float* mlp_b2     = (const float*)d_in[25];
  float* ws   = (float*)d_ws;
  float* outp = (float*)d_out;
  unsigned short* uw = (unsigned short*)(ws + WS_U);

  pre_amat_kernel<<<3, 256, 0, stream>>>(proj_w, k_w, v_w, ws);
  pre_dmat_kernel<<<128, 256, 0, stream>>>(fm, proj_w, proj_b, k_w, k_b, v_w, v_b, uw);
  pre_wfrag_kernel<<<(UW_WCNT + 255) / 256, 256, 0, stream>>>(
      q_w, o_w, mlp_w1, mlp_w2, attn_in_w, attn_out_w, uw);
  perceiver_kernel<<<512, 512, 0, stream>>>(
      x, latents, latent_pos, q_b, o_b,
      ln1_g, ln1_b, attn_in_b, attn_out_b,
      ln2_g, ln2_b, mlp_b1, mlp_b2, ws, outp);
}

// Round 4
// 5537.608 us; speedup vs baseline: 7.0117x; 1.1980x over previous
//
#include <hip/hip_runtime.h>
#include <cmath>

// float offsets in ws
#define WS_AK 0
#define WS_AV 300
#define WS_U  600   // ushort region starts here

// ushort offsets relative to uw = (ushort*)(ws + WS_U)
#define UW_DK   0          // bf16 [1024][104]
#define UW_DV   106496     // bf16 [104][1024]  (transposed)
#define UW_QW   212992     // q_w frags  kt4 x nt7
#define UW_OW   227328     // o_w frags  kt4 x nt7
#define UW_W1   241664     // + d*51200  kt4 x nt25
#define UW_W2   344064     // + d*50176  kt14 x nt7
#define UW_AIW  444416     // + (d*3+wsel)*16384  kt4 x nt8 (head-padded)
#define UW_AOW  542720     // + d*14336  kt4 x nt7 (head-padded k'=h*32+dh)
#define UW_WCNT 358400

typedef __attribute__((ext_vector_type(8))) short short8;
typedef __attribute__((ext_vector_type(4))) float f32x4;

#define MFMA(a, b, c) __builtin_amdgcn_mfma_f32_16x16x32_bf16((a), (b), (c), 0, 0, 0)

static __device__ __forceinline__ unsigned short f2bf(float f) {
  unsigned int u = __float_as_uint(f);
  u += 0x7FFF + ((u >> 16) & 1);   // RNE
  return (unsigned short)(u >> 16);
}
static __device__ __forceinline__ float bf2f(unsigned short u) {
  return __uint_as_float(((unsigned int)u) << 16);
}
static __device__ __forceinline__ f32x4 zero4() { return (f32x4){0.f, 0.f, 0.f, 0.f}; }

// ---------------------------------------------------------------------------
__global__ void pre_amat_kernel(const float* __restrict__ proj_w,
                                const float* __restrict__ k_w,
                                const float* __restrict__ v_w,
                                float* __restrict__ ws) {
  int idx = blockIdx.x * blockDim.x + threadIdx.x;
  if (idx >= 600) return;
  int sel = idx / 300;
  int rem = idx % 300;
  int c = rem / 100, m = rem % 100;
  const float* w = sel ? v_w : k_w;
  float acc = 0.f;
  for (int n = 0; n < 100; ++n) acc += proj_w[n * 131 + c] * w[m * 100 + n];
  ws[(sel ? WS_AV : WS_AK) + c * 100 + m] = acc;
}

// ---------------------------------------------------------------------------
__global__ void pre_dmat_kernel(const float* __restrict__ fm,
                                const float* __restrict__ proj_w,
                                const float* __restrict__ proj_b,
                                const float* __restrict__ k_w,
                                const float* __restrict__ k_b,
                                const float* __restrict__ v_w,
                                const float* __restrict__ v_b,
                                unsigned short* __restrict__ uw) {
  __shared__ float pos[8][128];
  __shared__ float tc[8][100];
  int p0 = blockIdx.x * 8;
  int tid = threadIdx.x;
  for (int idx = tid; idx < 1024; idx += 256) {
    int pl = idx >> 7, f = idx & 127;
    int p = p0 + pl;
    float cx = (float)(p & 31) * (1.f / 31.f);
    float cy = (float)(p >> 5) * (1.f / 31.f);
    int fi = f & 63;
    float pr = cx * fm[fi] + cy * fm[64 + fi];
    float ang = 6.2831853071795864769f * pr;
    pos[pl][f] = (f < 64) ? cosf(ang) : sinf(ang);
  }
  __syncthreads();
  for (int idx = tid; idx < 800; idx += 256) {
    int pl = idx / 100, n = idx % 100;
    float acc = proj_b[n];
    const float* pw = proj_w + n * 131 + 3;
    for (int f = 0; f < 128; ++f) acc += pos[pl][f] * pw[f];
    tc[pl][n] = acc;
  }
  __syncthreads();
  for (int idx = tid; idx < 1600; idx += 256) {
    int sel = idx / 800;
    int rem = idx % 800;
    int pl = rem / 100, m = rem % 100;
    const float* w = sel ? v_w : k_w;
    float acc = sel ? v_b[m] : k_b[m];
    for (int n = 0; n < 100; ++n) acc += tc[pl][n] * w[m * 100 + n];
    if (sel) uw[UW_DV + m * 1024 + (p0 + pl)] = f2bf(acc);
    else     uw[UW_DK + (p0 + pl) * 104 + m] = f2bf(acc);
  }
  for (int idx = tid; idx < 32; idx += 256) {
    int pl = idx >> 2, mm = 100 + (idx & 3);
    uw[UW_DK + (p0 + pl) * 104 + mm] = 0;
  }
}

// ---------------------------------------------------------------------------
__global__ void pre_wfrag_kernel(const float* __restrict__ q_w,
                                 const float* __restrict__ o_w,
                                 const float* __restrict__ mlp_w1,
                                 const float* __restrict__ mlp_w2,
                                 const float* __restrict__ attn_in_w,
                                 const float* __restrict__ attn_out_w,
                                 unsigned short* __restrict__ uw) {
  int idx = blockIdx.x * 256 + threadIdx.x;
  if (idx >= UW_WCNT) return;
  float val = 0.f;
  if (idx < 14336) {
    int rem = idx;
    int kt = rem / 3584; rem %= 3584;
    int nt = rem / 512;  rem %= 512;
    int lane = rem >> 3, j = rem & 7;
    int k = kt * 32 + (lane >> 4) * 8 + j;
    int n = nt * 16 + (lane & 15);
    if (k < 100 && n < 100) val = q_w[n * 100 + k];
  } else if (idx < 28672) {
    int rem = idx - 14336;
    int kt = rem / 3584; rem %= 3584;
    int nt = rem / 512;  rem %= 512;
    int lane = rem >> 3, j = rem & 7;
    int k = kt * 32 + (lane >> 4) * 8 + j;
    int n = nt * 16 + (lane & 15);
    if (k < 100 && n < 100) val = o_w[n * 100 + k];
  } else if (idx < 131072) {
    int off = idx - 28672;
    int dd = off / 51200;
    int rem = off % 51200;
    int kt = rem / 12800; rem %= 12800;
    int nt = rem / 512;   rem %= 512;
    int lane = rem >> 3, j = rem & 7;
    int k = kt * 32 + (lane >> 4) * 8 + j;
    int n = nt * 16 + (lane & 15);
    if (k < 100) val = mlp_w1[dd * 40000 + n * 100 + k];
  } else if (idx < 231424) {
    int off = idx - 131072;
    int dd = off / 50176;
    int rem = off % 50176;
    int kt = rem / 3584; rem %= 3584;
    int nt = rem / 512;  rem %= 512;
    int lane = rem >> 3, j = rem & 7;
    int k = kt * 32 + (lane >> 4) * 8 + j;
    int n = nt * 16 + (lane & 15);
    if (k < 400 && n < 100) val = mlp_w2[dd * 40000 + n * 400 + k];
  } else if (idx < 329728) {
    int off = idx - 231424;
    int dw = off / 16384;
    int rem = off % 16384;
    int dd = dw / 3, wsel = dw % 3;
    int kt = rem / 4096; rem %= 4096;
    int nt = rem / 512;  rem %= 512;
    int lane = rem >> 3, j = rem & 7;
    int k = kt * 32 + (lane >> 4) * 8 + j;
    int np = nt * 16 + (lane & 15);
    int hh = np >> 5, dh = np & 31;
    if (k < 100 && dh < 25)
      val = attn_in_w[dd * 30000 + (wsel * 100 + hh * 25 + dh) * 100 + k];
  } else {
    int off = idx - 329728;
    int dd = off / 14336;
    int rem = off % 14336;
    int kt = rem / 3584; rem %= 3584;
    int nt = rem / 512;  rem %= 512;
    int lane = rem >> 3, j = rem & 7;
    int kp = kt * 32 + (lane >> 4) * 8 + j;
    int hh = kp >> 5, dh = kp & 31;
    int n = nt * 16 + (lane & 15);
    if (dh < 25 && n < 100)
      val = attn_out_w[dd * 10000 + n * 100 + hh * 25 + dh];
  }
  uw[UW_QW + idx] = f2bf(val);
}

// ---------------------------------------------------------------------------
// Main kernel: 1 block/batch, 512 threads (8 waves), 2 blocks/CU (79 KB LDS).
// Residual lat lives in MFMA C-layout f32 regs: latC[mt2][nt][rg],
// row=(2wv+mt2)*16+lg*4+rg, col=nt*16+li.
// One 68KB LDS region R is time-shared by all phases.
// ---------------------------------------------------------------------------
__launch_bounds__(512, 4)
__global__ void perceiver_kernel(
    const float* __restrict__ x,
    const float* __restrict__ latents,
    const float* __restrict__ latent_pos,
    const float* __restrict__ q_b, const float* __restrict__ o_b,
    const float* __restrict__ ln1_g, const float* __restrict__ ln1_b,
    const float* __restrict__ attn_in_b, const float* __restrict__ attn_out_b,
    const float* __restrict__ ln2_g, const float* __restrict__ ln2_b,
    const float* __restrict__ mlp_b1, const float* __restrict__ mlp_b2,
    const float* __restrict__ ws,
    float* __restrict__ out) {
  __shared__ __align__(16) float s_pool[20208];
  float* s_sm = s_pool;                        // 2800 floats
  float* Rf   = s_pool + 2800;                 // 17408 floats = 34816 ushorts
  unsigned short* R   = (unsigned short*)Rf;
  unsigned short* s_M = R;                     // [256][132] bf16 staging
  unsigned short* sK  = R;                     // [16][64][8]
  unsigned short* sV  = R + 8192;              // [8][112][8]
  unsigned short* sP  = R + 15360;             // [256][76]
  unsigned short* sQh   = R;                   // [256][36]
  unsigned short* kfrag = R + 9216;            // 8192
  unsigned short* vfrag = R + 17408;           // 8192
  unsigned short* sPm   = R + 25600;           // [256][36], reused for Oh

  const int tid  = threadIdx.x;
  const int b    = blockIdx.x;
  const int lane = tid & 63;
  const int wv   = tid >> 6;
  const int li   = lane & 15;
  const int lg   = lane >> 4;
  const unsigned short* uw = (const unsigned short*)(ws + WS_U);

  // ---- stage hot constants ----
  for (int i = tid; i < 200; i += 512) {
    s_sm[i] = ln1_g[i]; s_sm[200 + i] = ln1_b[i];
    s_sm[400 + i] = ln2_g[i]; s_sm[600 + i] = ln2_b[i];
  }
  for (int i = tid; i < 600; i += 512) s_sm[800 + i] = attn_in_b[i];
  for (int i = tid; i < 800; i += 512) s_sm[1400 + i] = mlp_b1[i];
  for (int i = tid; i < 300; i += 512) { s_sm[2200 + i] = ws[WS_AK + i]; s_sm[2500 + i] = ws[WS_AV + i]; }

  // ---- residual in C-layout regs ----
  f32x4 latC[2][7];
  #pragma unroll
  for (int mt2 = 0; mt2 < 2; ++mt2)
    #pragma unroll
    for (int nt = 0; nt < 7; ++nt) {
      const int col = nt * 16 + li;
      #pragma unroll
      for (int rg = 0; rg < 4; ++rg) {
        const int row = (2 * wv + mt2) * 16 + lg * 4 + rg;
        latC[mt2][nt][rg] = (col < 100)
            ? latents[row * 100 + col] + latent_pos[row * 100 + col] : 0.f;
      }
    }

  const float* xb = x + (long)b * 3072;

  // LN helper: latC -> s_M (bf16, zero-padded cols 100..127)
  auto ln_stage = [&](const float* gg, const float* bb) {
    #pragma unroll
    for (int mt2 = 0; mt2 < 2; ++mt2)
      #pragma unroll
      for (int rg = 0; rg < 4; ++rg) {
        float s = 0.f, sq = 0.f;
        #pragma unroll
        for (int nt = 0; nt < 7; ++nt) {
          const int col = nt * 16 + li;
          if (col < 100) { const float v = latC[mt2][nt][rg]; s += v; sq += v * v; }
        }
        s += __shfl_xor(s, 1); sq += __shfl_xor(sq, 1);
        s += __shfl_xor(s, 2); sq += __shfl_xor(sq, 2);
        s += __shfl_xor(s, 4); sq += __shfl_xor(sq, 4);
        s += __shfl_xor(s, 8); sq += __shfl_xor(sq, 8);
        const float mu = s * 0.01f;
        const float rs = rsqrtf(sq * 0.01f - mu * mu + 1e-5f);
        const int row = (2 * wv + mt2) * 16 + lg * 4 + rg;
        #pragma unroll
        for (int nt = 0; nt < 7; ++nt) {
          const int col = nt * 16 + li;
          s_M[row * 132 + col] = (col < 100)
              ? f2bf((latC[mt2][nt][rg] - mu) * rs * gg[col] + bb[col]) : 0;
        }
        s_M[row * 132 + 112 + li] = 0;
      }
  };

  for (int it = 0; it < 8; ++it) {
    //=================== cross attention ===================
    // stage lat -> s_M (own-wave rows only; no barrier needed vs prev phase)
    #pragma unroll
    for (int mt2 = 0; mt2 < 2; ++mt2)
      #pragma unroll
      for (int rg = 0; rg < 4; ++rg) {
        const int row = (2 * wv + mt2) * 16 + lg * 4 + rg;
        #pragma unroll
        for (int nt = 0; nt < 7; ++nt) {
          const int col = nt * 16 + li;
          s_M[row * 132 + col] = (col < 100) ? f2bf(latC[mt2][nt][rg]) : 0;
        }
        s_M[row * 132 + 112 + li] = 0;
      }

    // q-proj: q = (lat @ q_w^T + q_b) * 0.1, write back into s_M
    {
      short8 aq[2][4];
      #pragma unroll
      for (int mt2 = 0; mt2 < 2; ++mt2)
        #pragma unroll
        for (int kt = 0; kt < 4; ++kt)
          aq[mt2][kt] = *(const short8*)(s_M + ((2 * wv + mt2) * 16 + li) * 132 + kt * 32 + lg * 8);
      #pragma unroll
      for (int nt = 0; nt < 7; ++nt) {
        f32x4 a0 = zero4(), a1 = zero4();
        #pragma unroll
        for (int kt = 0; kt < 4; ++kt) {
          short8 bw = *(const short8*)(uw + UW_QW + ((kt * 7 + nt) * 64 + lane) * 8);
          a0 = MFMA(aq[0][kt], bw, a0);
          a1 = MFMA(aq[1][kt], bw, a1);
        }
        const int col = nt * 16 + li;
        const float qb = (col < 100) ? q_b[col] : 0.f;
        #pragma unroll
        for (int rg = 0; rg < 4; ++rg) {
          const int r0 = (2 * wv) * 16 + lg * 4 + rg;
          const int r1 = (2 * wv + 1) * 16 + lg * 4 + rg;
          s_M[r0 * 132 + col] = (col < 100) ? f2bf((a0[rg] + qb) * 0.1f) : 0;
          s_M[r1 * 132 + col] = (col < 100) ? f2bf((a1[rg] + qb) * 0.1f) : 0;
        }
      }
    }

    // q A-frags
    short8 aq2[2][4];
    #pragma unroll
    for (int mt2 = 0; mt2 < 2; ++mt2)
      #pragma unroll
      for (int kt = 0; kt < 4; ++kt)
        aq2[mt2][kt] = *(const short8*)(s_M + ((2 * wv + mt2) * 16 + li) * 132 + kt * 32 + lg * 8);

    // O = exp(q@K^T) @ [V|1]
    f32x4 O[2][7];
    #pragma unroll
    for (int a0 = 0; a0 < 2; ++a0)
      #pragma unroll
      for (int a1 = 0; a1 < 7; ++a1) O[a0][a1] = zero4();

    for (int t0 = 0; t0 < 1024; t0 += 64) {
      __syncthreads();   // all waves done with R (q frags loaded / prev tile)
      for (int vi = tid; vi < 1024; vi += 512) {
        const int key = vi & 63, cg = vi >> 6;
        const int p = t0 + key;
        short8 w;
        if (cg < 13) {
          const float xr = xb[p], xg = xb[1024 + p], xv = xb[2048 + p];
          short8 dk = *(const short8*)(uw + UW_DK + p * 104 + cg * 8);
          #pragma unroll
          for (int e = 0; e < 8; ++e) {
            const int c = cg * 8 + e;
            float val = 0.f;
            if (c < 100)
              val = xr * s_sm[2200 + c] + xg * s_sm[2300 + c] + xv * s_sm[2400 + c]
                  + bf2f((unsigned short)dk[e]);
            w[e] = (short)f2bf(val);
          }
        } else {
          #pragma unroll
          for (int e = 0; e < 8; ++e) w[e] = 0;
        }
        *(short8*)(sK + vi * 8) = w;
      }
      for (int vi = tid; vi < 896; vi += 512) {
        const int ch = vi % 112, kg = vi / 112;
        const int pv0 = t0 + kg * 8;
        short8 w;
        if (ch < 100) {
          const float4 xr0 = *(const float4*)(xb + pv0);
          const float4 xr1 = *(const float4*)(xb + pv0 + 4);
          const float4 xg0 = *(const float4*)(xb + 1024 + pv0);
          const float4 xg1 = *(const float4*)(xb + 1024 + pv0 + 4);
          const float4 xv0 = *(const float4*)(xb + 2048 + pv0);
          const float4 xv1 = *(const float4*)(xb + 2048 + pv0 + 4);
          short8 dv = *(const short8*)(uw + UW_DV + ch * 1024 + pv0);
          const float a0 = s_sm[2500 + ch], a1 = s_sm[2600 + ch], a2 = s_sm[2700 + ch];
          const float xrv[8] = {xr0.x, xr0.y, xr0.z, xr0.w, xr1.x, xr1.y, xr1.z, xr1.w};
          const float xgv[8] = {xg0.x, xg0.y, xg0.z, xg0.w, xg1.x, xg1.y, xg1.z, xg1.w};
          const float xvv[8] = {xv0.x, xv0.y, xv0.z, xv0.w, xv1.x, xv1.y, xv1.z, xv1.w};
          #pragma unroll
          for (int e = 0; e < 8; ++e)
            w[e] = (short)f2bf(xrv[e] * a0 + xgv[e] * a1 + xvv[e] * a2
                               + bf2f((unsigned short)dv[e]));
        } else if (ch == 100) {
          #pragma unroll
          for (int e = 0; e < 8; ++e) w[e] = (short)0x3F80;
        } else {
          #pragma unroll
          for (int e = 0; e < 8; ++e) w[e] = 0;
        }
        *(short8*)(sV + vi * 8) = w;
      }
      __syncthreads();

      // S-GEMM + exp -> sP
      #pragma unroll
      for (int ntk = 0; ntk < 4; ++ntk) {
        f32x4 s0 = zero4(), s1 = zero4();
        #pragma unroll
        for (int kt = 0; kt < 4; ++kt) {
          short8 bk = *(const short8*)(sK + ((kt * 4 + lg) * 64 + ntk * 16 + li) * 8);
          s0 = MFMA(aq2[0][kt], bk, s0);
          s1 = MFMA(aq2[1][kt], bk, s1);
        }
        #pragma unroll
        for (int rg = 0; rg < 4; ++rg) {
          const int r0 = (2 * wv) * 16 + lg * 4 + rg;
          const int r1 = (2 * wv + 1) * 16 + lg * 4 + rg;
          sP[r0 * 76 + ntk * 16 + li] = f2bf(__expf(s0[rg]));
          sP[r1 * 76 + ntk * 16 + li] = f2bf(__expf(s1[rg]));
        }
      }
      // PV
      short8 ap[2][2];
      #pragma unroll
      for (int mt2 = 0; mt2 < 2; ++mt2)
        #pragma unroll
        for (int kt2 = 0; kt2 < 2; ++kt2)
          ap[mt2][kt2] = *(const short8*)(sP + ((2 * wv + mt2) * 16 + li) * 76 + kt2 * 32 + lg * 8);
      #pragma unroll
      for (int nt = 0; nt < 7; ++nt) {
        short8 bv0 = *(const short8*)(sV + ((0 + lg) * 112 + nt * 16 + li) * 8);
        short8 bv1 = *(const short8*)(sV + ((4 + lg) * 112 + nt * 16 + li) * 8);
        #pragma unroll
        for (int mt2 = 0; mt2 < 2; ++mt2) {
          O[mt2][nt] = MFMA(ap[mt2][0], bv0, O[mt2][nt]);
          O[mt2][nt] = MFMA(ap[mt2][1], bv1, O[mt2][nt]);
        }
      }
    }
    __syncthreads();   // all tile reads done before s_M overwrite

    // normalize (l at col 100 -> nt=6, li==4), write o_in -> s_M
    #pragma unroll
    for (int mt2 = 0; mt2 < 2; ++mt2)
      #pragma unroll
      for (int rg = 0; rg < 4; ++rg) {
        const float lv = __shfl(O[mt2][6][rg], (lane & 48) + 4);
        const float linv = 1.0f / lv;
        const int row = (2 * wv + mt2) * 16 + lg * 4 + rg;
        #pragma unroll
        for (int nt = 0; nt < 7; ++nt) {
          const int col = nt * 16 + li;
          s_M[row * 132 + col] = (col < 100) ? f2bf(O[mt2][nt][rg] * linv) : 0;
        }
        s_M[row * 132 + 112 + li] = 0;
      }

    // o-proj -> latC (replace)
    {
      short8 ao[2][4];
      #pragma unroll
      for (int mt2 = 0; mt2 < 2; ++mt2)
        #pragma unroll
        for (int kt = 0; kt < 4; ++kt)
          ao[mt2][kt] = *(const short8*)(s_M + ((2 * wv + mt2) * 16 + li) * 132 + kt * 32 + lg * 8);
      #pragma unroll
      for (int nt = 0; nt < 7; ++nt) {
        f32x4 a0 = zero4(), a1 = zero4();
        #pragma unroll
        for (int kt = 0; kt < 4; ++kt) {
          short8 bw = *(const short8*)(uw + UW_OW + ((kt * 7 + nt) * 64 + lane) * 8);
          a0 = MFMA(ao[0][kt], bw, a0);
          a1 = MFMA(ao[1][kt], bw, a1);
        }
        const int col = nt * 16 + li;
        const float ob = (col < 100) ? o_b[col] : 0.f;
        #pragma unroll
        for (int rg = 0; rg < 4; ++rg) {
          latC[0][nt][rg] = (col < 100) ? a0[rg] + ob : 0.f;
          latC[1][nt][rg] = (col < 100) ? a1[rg] + ob : 0.f;
        }
      }
    }

    //=================== latent transformer ===================
    for (int d = 0; d < 2; ++d) {
      // ---- LN1 -> s_M (own rows)
      ln_stage(&s_sm[d * 100], &s_sm[200 + d * 100]);
      short8 ah[2][4];
      #pragma unroll
      for (int mt2 = 0; mt2 < 2; ++mt2)
        #pragma unroll
        for (int kt = 0; kt < 4; ++kt)
          ah[mt2][kt] = *(const short8*)(s_M + ((2 * wv + mt2) * 16 + li) * 132 + kt * 32 + lg * 8);

      // co init = lat + attn_out_b (residual + bias)
      f32x4 co[2][7];
      #pragma unroll
      for (int nt = 0; nt < 7; ++nt) {
        const int col = nt * 16 + li;
        const float ob = (col < 100) ? attn_out_b[d * 100 + col] : 0.f;
        #pragma unroll
        for (int rg = 0; rg < 4; ++rg) {
          co[0][nt][rg] = (col < 100) ? latC[0][nt][rg] + ob : 0.f;
          co[1][nt][rg] = (col < 100) ? latC[1][nt][rg] + ob : 0.f;
        }
      }

      for (int h = 0; h < 4; ++h) {
        __syncthreads();   // prior reads of R complete before scratch writes
        // QKV GEMMs (own 32 rows), per ntd to cap live accumulators
        #pragma unroll
        for (int ntd = 0; ntd < 2; ++ntd) {
          f32x4 cq0 = zero4(), cq1 = zero4(), ck0 = zero4(), ck1 = zero4(),
                cv0 = zero4(), cv1 = zero4();
          #pragma unroll
          for (int kt = 0; kt < 4; ++kt) {
            const int bidx = ((kt * 8 + h * 2 + ntd) * 64 + lane) * 8;
            short8 bq  = *(const short8*)(uw + UW_AIW + (d * 3 + 0) * 16384 + bidx);
            short8 bkk = *(const short8*)(uw + UW_AIW + (d * 3 + 1) * 16384 + bidx);
            short8 bvv = *(const short8*)(uw + UW_AIW + (d * 3 + 2) * 16384 + bidx);
            cq0 = MFMA(ah[0][kt], bq,  cq0); cq1 = MFMA(ah[1][kt], bq,  cq1);
            ck0 = MFMA(ah[0][kt], bkk, ck0); ck1 = MFMA(ah[1][kt], bkk, ck1);
            cv0 = MFMA(ah[0][kt], bvv, cv0); cv1 = MFMA(ah[1][kt], bvv, cv1);
          }
          const int dh = ntd * 16 + li;
          const bool ok = dh < 25;
          const float qb2 = ok ? s_sm[800 + d * 300 +       h * 25 + dh] : 0.f;
          const float kb2 = ok ? s_sm[800 + d * 300 + 100 + h * 25 + dh] : 0.f;
          const float vb2 = ok ? s_sm[800 + d * 300 + 200 + h * 25 + dh] : 0.f;
          #pragma unroll
          for (int mt2 = 0; mt2 < 2; ++mt2)
            #pragma unroll
            for (int rg = 0; rg < 4; ++rg) {
              const int rr = lg * 4 + rg;
              const int row = (2 * wv + mt2) * 16 + rr;
              const float q = mt2 ? cq1[rg] : cq0[rg];
              const float k = mt2 ? ck1[rg] : ck0[rg];
              const float v = mt2 ? cv1[rg] : cv0[rg];
              sQh[row * 36 + dh] = ok ? f2bf((q + qb2) * 0.2f) : 0;
              kfrag[((2 * wv + mt2) * 64 + (dh >> 3) * 16 + rr) * 8 + (dh & 7)] =
                  ok ? f2bf(k + kb2) : 0;
              vfrag[((wv * 2 + ntd) * 64 + (mt2 * 2 + (rr >> 3)) * 16 + li) * 8 + (rr & 7)] =
                  ok ? f2bf(v + vb2) : (unsigned short)((dh == 25) ? 0x3F80 : 0);
            }
        }
        __syncthreads();   // kfrag/vfrag visible

        short8 aqh0 = *(const short8*)(sQh + ((2 * wv + 0) * 16 + li) * 36 + lg * 8);
        short8 aqh1 = *(const short8*)(sQh + ((2 * wv + 1) * 16 + li) * 36 + lg * 8);
        f32x4 Oh00 = zero4(), Oh01 = zero4(), Oh10 = zero4(), Oh11 = zero4();
        for (int t = 0; t < 8; ++t) {
          short8 bk0 = *(const short8*)(kfrag + ((t * 2 + 0) * 64 + lane) * 8);
          short8 bk1 = *(const short8*)(kfrag + ((t * 2 + 1) * 64 + lane) * 8);
          f32x4 s00 = MFMA(aqh0, bk0, zero4());
          f32x4 s01 = MFMA(aqh0, bk1, zero4());
          f32x4 s10 = MFMA(aqh1, bk0, zero4());
          f32x4 s11 = MFMA(aqh1, bk1, zero4());
          #pragma unroll
          for (int rg = 0; rg < 4; ++rg) {
            const int r0 = (2 * wv) * 16 + lg * 4 + rg;
            const int r1 = (2 * wv + 1) * 16 + lg * 4 + rg;
            sPm[r0 * 36 + li]      = f2bf(__expf(s00[rg]));
            sPm[r0 * 36 + 16 + li] = f2bf(__expf(s01[rg]));
            sPm[r1 * 36 + li]      = f2bf(__expf(s10[rg]));
            sPm[r1 * 36 + 16 + li] = f2bf(__expf(s11[rg]));
          }
          short8 ap0 = *(const short8*)(sPm + ((2 * wv + 0) * 16 + li) * 36 + lg * 8);
          short8 ap1 = *(const short8*)(sPm + ((2 * wv + 1) * 16 + li) * 36 + lg * 8);
          short8 bv0 = *(const short8*)(vfrag + ((t * 2 + 0) * 64 + lane) * 8);
          short8 bv1 = *(const short8*)(vfrag + ((t * 2 + 1) * 64 + lane) * 8);
          Oh00 = MFMA(ap0, bv0, Oh00); Oh01 = MFMA(ap0, bv1, Oh01);
          Oh10 = MFMA(ap1, bv0, Oh10); Oh11 = MFMA(ap1, bv1, Oh11);
        }
        // normalize (l at dh=25 -> li==9 in tile 1), stage Oh into sPm slot
        #pragma unroll
        for (int mt2 = 0; mt2 < 2; ++mt2)
          #pragma unroll
          for (int rg = 0; rg < 4; ++rg) {
            const f32x4& o0 = mt2 ? Oh10 : Oh00;
            const f32x4& o1 = mt2 ? Oh11 : Oh01;
            const float lv = __shfl(o1[rg], (lane & 48) + 9);
            const float linv = 1.0f / lv;
            const int row = (2 * wv + mt2) * 16 + lg * 4 + rg;
            sPm[row * 36 + li]      = (li < 25)      ? f2bf(o0[rg] * linv) : 0;
            sPm[row * 36 + 16 + li] = (16 + li < 25) ? f2bf(o1[rg] * linv) : 0;
          }
        // co += Oh @ AOW[kt=h]
        short8 ao0 = *(const short8*)(sPm + ((2 * wv + 0) * 16 + li) * 36 + lg * 8);
        short8 ao1 = *(const short8*)(sPm + ((2 * wv + 1) * 16 + li) * 36 + lg * 8);
        #pragma unroll
        for (int nt = 0; nt < 7; ++nt) {
          short8 bw = *(const short8*)(uw + UW_AOW + d * 14336 + ((h * 7 + nt) * 64 + lane) * 8);
          co[0][nt] = MFMA(ao0, bw, co[0][nt]);
          co[1][nt] = MFMA(ao1, bw, co[1][nt]);
        }
      }
      __syncthreads();   // all scratch reads done

      #pragma unroll
      for (int mt2 = 0; mt2 < 2; ++mt2)
        #pragma unroll
        for (int nt = 0; nt < 7; ++nt) latC[mt2][nt] = co[mt2][nt];

      // ---- LN2 -> s_M, MLP
      ln_stage(&s_sm[400 + d * 100], &s_sm[600 + d * 100]);
      short8 ahm[2][4];
      #pragma unroll
      for (int mt2 = 0; mt2 < 2; ++mt2)
        #pragma unroll
        for (int kt = 0; kt < 4; ++kt)
          ahm[mt2][kt] = *(const short8*)(s_M + ((2 * wv + mt2) * 16 + li) * 132 + kt * 32 + lg * 8);

      f32x4 c2[2][7];
      #pragma unroll
      for (int nt = 0; nt < 7; ++nt) {
        const int col = nt * 16 + li;
        const float b2 = (col < 100) ? mlp_b2[d * 100 + col] : 0.f;
        #pragma unroll
        for (int rg = 0; rg < 4; ++rg) {
          c2[0][nt][rg] = (col < 100) ? latC[0][nt][rg] + b2 : 0.f;
          c2[1][nt][rg] = (col < 100) ? latC[1][nt][rg] + b2 : 0.f;
        }
      }

      const int w1off = UW_W1 + d * 51200;
      const int w2off = UW_W2 + d * 50176;
      for (int chunk = 0; chunk < 3; ++chunk) {
        #pragma unroll
        for (int ntl = 0; ntl < 8; ++ntl) {
          f32x4 a0 = zero4(), a1 = zero4();
          #pragma unroll
          for (int kt = 0; kt < 4; ++kt) {
            short8 bw = *(const short8*)(uw + w1off + ((kt * 25 + (chunk * 8 + ntl)) * 64 + lane) * 8);
            a0 = MFMA(ahm[0][kt], bw, a0);
            a1 = MFMA(ahm[1][kt], bw, a1);
          }
          const int col = ntl * 16 + li;
          const float bias = s_sm[1400 + d * 400 + chunk * 128 + col];
          #pragma unroll
          for (int rg = 0; rg < 4; ++rg) {
            const int r0 = (2 * wv) * 16 + lg * 4 + rg;
            const int r1 = (2 * wv + 1) * 16 + lg * 4 + rg;
            float h0 = a0[rg] + bias, h1 = a1[rg] + bias;
            s_M[r0 * 132 + col] = f2bf(0.5f * h0 * (1.0f + erff(h0 * 0.70710678118654752f)));
            s_M[r1 * 132 + col] = f2bf(0.5f * h1 * (1.0f + erff(h1 * 0.70710678118654752f)));
          }
        }
        #pragma unroll
        for (int ktl = 0; ktl < 4; ++ktl) {
          short8 ahh0 = *(const short8*)(s_M + ((2 * wv + 0) * 16 + li) * 132 + ktl * 32 + lg * 8);
          short8 ahh1 = *(const short8*)(s_M + ((2 * wv + 1) * 16 + li) * 132 + ktl * 32 + lg * 8);
          #pragma unroll
          for (int nt = 0; nt < 7; ++nt) {
            short8 bw = *(const short8*)(uw + w2off + (((chunk * 4 + ktl) * 7 + nt) * 64 + lane) * 8);
            c2[0][nt] = MFMA(ahh0, bw, c2[0][nt]);
            c2[1][nt] = MFMA(ahh1, bw, c2[1][nt]);
          }
        }
      }
      {   // chunk 3: hidden 384..399
        f32x4 a0 = zero4(), a1 = zero4();
        #pragma unroll
        for (int kt = 0; kt < 4; ++kt) {
          short8 bw = *(const short8*)(uw + w1off + ((kt * 25 + 24) * 64 + lane) * 8);
          a0 = MFMA(ahm[0][kt], bw, a0);
          a1 = MFMA(ahm[1][kt], bw, a1);
        }
        const float bias = s_sm[1400 + d * 400 + 384 + li];
        #pragma unroll
        for (int rg = 0; rg < 4; ++rg) {
          const int r0 = (2 * wv) * 16 + lg * 4 + rg;
          const int r1 = (2 * wv + 1) * 16 + lg * 4 + rg;
          float h0 = a0[rg] + bias, h1 = a1[rg] + bias;
          s_M[r0 * 132 + li] = f2bf(0.5f * h0 * (1.0f + erff(h0 * 0.70710678118654752f)));
          s_M[r1 * 132 + li] = f2bf(0.5f * h1 * (1.0f + erff(h1 * 0.70710678118654752f)));
          s_M[r0 * 132 + 16 + li] = 0;
          s_M[r1 * 132 + 16 + li] = 0;
        }
        short8 ahh0 = *(const short8*)(s_M + ((2 * wv + 0) * 16 + li) * 132 + lg * 8);
        short8 ahh1 = *(const short8*)(s_M + ((2 * wv + 1) * 16 + li) * 132 + lg * 8);
        #pragma unroll
        for (int nt = 0; nt < 7; ++nt) {
          short8 bw = *(const short8*)(uw + w2off + ((12 * 7 + nt) * 64 + lane) * 8);
          c2[0][nt] = MFMA(ahh0, bw, c2[0][nt]);
          c2[1][nt] = MFMA(ahh1, bw, c2[1][nt]);
        }
      }
      #pragma unroll
      for (int mt2 = 0; mt2 < 2; ++mt2)
        #pragma unroll
        for (int nt = 0; nt < 7; ++nt) latC[mt2][nt] = c2[mt2][nt];
    }
  }

  //=================== mean over 256 latents ===================
  __syncthreads();
  #pragma unroll
  for (int nt = 0; nt < 7; ++nt) {
    float v = 0.f;
    #pragma unroll
    for (int rg = 0; rg < 4; ++rg) v += latC[0][nt][rg] + latC[1][nt][rg];
    v += __shfl_xor(v, 16);
    v += __shfl_xor(v, 32);
    if (lg == 0) Rf[wv * 112 + nt * 16 + li] = v;
  }
  __syncthreads();
  if (tid < 100) {
    float s = 0.f;
    #pragma unroll
    for (int w = 0; w < 8; ++w) s += Rf[w * 112 + tid];
    out[b * 100 + tid] = s * (1.0f / 256.0f);
  }
}

// ---------------------------------------------------------------------------
extern "C" void kernel_launch(void* const* d_in, const int* in_sizes, int n_in,
                              void* d_out, int out_size, void* d_ws, size_t ws_size,
                              hipStream_t stream) {
  (void)in_sizes; (void)n_in; (void)out_size; (void)ws_size;
  const float* x          = (const float*)d_in[0];
  const float* latents    = (const float*)d_in[1];
  const float* latent_pos = (const float*)d_in[2];
  const float* fm         = (const float*)d_in[3];
  const float* proj_w     = (const float*)d_in[4];
  const float* proj_b     = (const float*)d_in[5];
  const float* q_w        = (const float*)d_in[6];
  const float* q_b        = (const float*)d_in[7];
  const float* k_w        = (const float*)d_in[8];
  const float* k_b        = (const float*)d_in[9];
  const float* v_w        = (const float*)d_in[10];
  const float* v_b        = (const float*)d_in[11];
  const float* o_w        = (const float*)d_in[12];
  const float* o_b        = (const float*)d_in[13];
  const float* ln1_g      = (const float*)d_in[14];
  const float* ln1_b      = (const float*)d_in[15];
  const float* attn_in_w  = (const float*)d_in[16];
  const float* attn_in_b  = (const float*)d_in[17];
  const float* attn_out_w = (const float*)d_in[18];
  const float* attn_out_b = (const float*)d_in[19];
  const float* ln2_g      = (const float*)d_in[20];
  const float* ln2_b      = (const float*)d_in[21];
  const float* mlp_w1     = (const float*)d_in[22];
  const float* mlp_b1     = (const float*)d_in[23];
  const float* mlp_w2     = (const float*)d_in[24];
  const float* mlp_b2     = (const float*)d_in[25];
  float* ws   = (float*)d_ws;
  float* outp = (float*)d_out;
  unsigned short* uw = (unsigned short*)(ws + WS_U);

  pre_amat_kernel<<<3, 256, 0, stream>>>(proj_w, k_w, v_w, ws);
  pre_dmat_kernel<<<128, 256, 0, stream>>>(fm, proj_w, proj_b, k_w, k_b, v_w, v_b, uw);
  pre_wfrag_kernel<<<(UW_WCNT + 255) / 256, 256, 0, stream>>>(
      q_w, o_w, mlp_w1, mlp_w2, attn_in_w, attn_out_w, uw);
  perceiver_kernel<<<512, 512, 0, stream>>>(
      x, latents, latent_pos, q_b, o_b,
      ln1_g, ln1_b, attn_in_b, attn_out_b,
      ln2_g, ln2_b, mlp_b1, mlp_b2, ws, outp);
}